// Round 12
// baseline (2208.658 us; speedup 1.0000x reference)
//
#include <hip/hip_runtime.h>

typedef short v8s __attribute__((ext_vector_type(8)));
typedef float v4f __attribute__((ext_vector_type(4)));
typedef unsigned short u16;

#define DI __device__ __forceinline__
#define MFMA(a, b, c) __builtin_amdgcn_mfma_f32_16x16x32_bf16(a, b, c, 0, 0, 0)

constexpr int B = 32, S = 64, T = 48, E = 512, H = 1024, V = 32000;
constexpr int TP = T - 1;        // 47 prediction steps
constexpr int MROWS = TP * B;    // 1504 valid proj rows
constexpr int NCH = 250;         // 32000 / 128 vocab chunks

DI u16 f2bf(float f) {
    unsigned u = __float_as_uint(f);
    unsigned r = (u + 0x7FFFu + ((u >> 16) & 1u)) >> 16;
    return (u16)r;
}
DI float bf2f(u16 h) { return __uint_as_float(((unsigned)h) << 16); }
DI v8s load8(const u16* p) { return *reinterpret_cast<const v8s*>(p); }

typedef __attribute__((address_space(1))) const unsigned int gu32;
typedef __attribute__((address_space(3))) unsigned int lu32;
DI void gload_lds16(const u16* g, u16* l) {
    __builtin_amdgcn_global_load_lds((gu32*)g, (lu32*)l, 16, 0, 0);
}

// coherence-point u32 store (bypasses private L2; visible to all XCDs)
DI void cstore(unsigned* p, unsigned v) {
    __hip_atomic_store(p, v, __ATOMIC_RELAXED, __HIP_MEMORY_SCOPE_AGENT);
}
DI int cload(const int* p) {
    return __hip_atomic_load(p, __ATOMIC_RELAXED, __HIP_MEMORY_SCOPE_AGENT);
}

// ---------------- root-scan grid barrier (R5/R9 proven) ----------------------
DI void gbar2(int* bar, int bid, int nblk, int v) {
    __syncthreads();
    if (bid == 0) {
        int t = threadIdx.x;
        if (t > 0 && t < nblk) {
            while (cload(bar + 16 + t * 4) < v) __builtin_amdgcn_s_sleep(1);
        }
        __syncthreads();
        if (t == 0)
            __hip_atomic_store(bar, v, __ATOMIC_RELAXED, __HIP_MEMORY_SCOPE_AGENT);
    } else {
        if (threadIdx.x == 0) {
            __hip_atomic_store(bar + 16 + bid * 4, v, __ATOMIC_RELAXED,
                               __HIP_MEMORY_SCOPE_AGENT);
            while (cload(bar) < v) __builtin_amdgcn_s_sleep(2);
        }
        __syncthreads();
    }
}

// ---------------- elementwise conversion f32 -> bf16 ----------------
__global__ __launch_bounds__(256) void k_cvt(const float* __restrict__ s,
                                             u16* __restrict__ d, int n4) {
    int i = blockIdx.x * 256 + threadIdx.x;
    if (i >= n4) return;
    float4 v = reinterpret_cast<const float4*>(s)[i];
    ushort4 o;
    o.x = f2bf(v.x); o.y = f2bf(v.y); o.z = f2bf(v.z); o.w = f2bf(v.w);
    reinterpret_cast<ushort4*>(d)[i] = o;
}

// ---------------- merged multi-segment conversion ----------------
struct CvtD {
    const float* src[11];
    u16* dst[11];
    int n4[11];
    int start[12];
};
__global__ __launch_bounds__(256) void k_cvtm(CvtD d) {
    int blk = blockIdx.x;
    int seg = 0;
    #pragma unroll
    for (int q = 0; q < 11; ++q)
        if (blk >= d.start[q + 1]) seg = q + 1;
    int i = (blk - d.start[seg]) * 256 + threadIdx.x;
    if (i >= d.n4[seg]) return;
    float4 v = reinterpret_cast<const float4*>(d.src[seg])[i];
    ushort4 o;
    o.x = f2bf(v.x); o.y = f2bf(v.y); o.z = f2bf(v.z); o.w = f2bf(v.w);
    reinterpret_cast<ushort4*>(d.dst[seg])[i] = o;
}

// ---------------- embedding gather ----------------
__global__ __launch_bounds__(256) void k_embed(const int* __restrict__ seq, int seqstr,
                                               int nsteps, const float* __restrict__ emb,
                                               u16* __restrict__ out) {
    int i = blockIdx.x * 256 + threadIdx.x;
    int total = nsteps * B * (E / 4);
    if (i >= total) return;
    int q = i & 127;
    int sb = i >> 7;
    int b = sb & 31;
    int s = sb >> 5;
    int tok = seq[b * seqstr + s];
    float4 v = reinterpret_cast<const float4*>(emb + (size_t)tok * E)[q];
    ushort4 o;
    o.x = f2bf(v.x); o.y = f2bf(v.y); o.z = f2bf(v.z); o.w = f2bf(v.w);
    reinterpret_cast<ushort4*>(out + ((size_t)(s * B + b)) * E)[q] = o;
}

// ---------------- build ench[b][s][2H] from hsf/hsb ----------------
__global__ __launch_bounds__(256) void k_ench(const u16* __restrict__ hsf,
                                              const u16* __restrict__ hsb,
                                              u16* __restrict__ ench) {
    int id = blockIdx.x * 256 + threadIdx.x;
    int d8 = id & 255; int s = (id >> 8) & 63; int b = id >> 14;
    int d0 = d8 * 8;
    const u16* src = (d0 < H) ? hsf + (((size_t)(s + 1) * B + b)) * H + d0
                              : hsb + (((size_t)(S - s) * B + b)) * H + (d0 - H);
    *reinterpret_cast<v8s*>(ench + ((size_t)b * S + s) * 2 * H + d0) = load8(src);
}

// ---------------- transpose: out[n][k] = in[k][n], in K x N -----------------
__global__ __launch_bounds__(256) void k_transp(const u16* __restrict__ in,
                                                u16* __restrict__ out, int K, int N) {
    __shared__ u16 t[64][72];
    int nt = blockIdx.x * 64, kt = blockIdx.y * 64;
    int tid = threadIdx.x;
    int r = tid >> 2, cq = (tid & 3) * 16;
    v8s v0 = load8(in + (size_t)(kt + r) * N + nt + cq);
    v8s v1 = load8(in + (size_t)(kt + r) * N + nt + cq + 8);
    #pragma unroll
    for (int e = 0; e < 8; ++e) { t[r][cq + e] = (u16)v0[e]; t[r][cq + 8 + e] = (u16)v1[e]; }
    __syncthreads();
    v8s o0, o1;
    #pragma unroll
    for (int e = 0; e < 8; ++e) { o0[e] = (short)t[cq + e][r]; o1[e] = (short)t[cq + 8 + e][r]; }
    *reinterpret_cast<v8s*>(out + (size_t)(nt + r) * K + kt + cq) = o0;
    *reinterpret_cast<v8s*>(out + (size_t)(nt + r) * K + kt + cq + 8) = o1;
}

// ---------------- generic tiled GEMM: out = A @ W^T (128x128 tile) ----------
__global__ __launch_bounds__(256) void k_tile(const u16* __restrict__ A, int astr,
                                              const u16* __restrict__ W, int wstr,
                                              float* __restrict__ outf,
                                              u16* __restrict__ outb, int ostr,
                                              int ktiles) {
    __shared__ __align__(16) u16 As[128 * 64];
    __shared__ __align__(16) u16 Bs[128 * 64];
    const int tid = threadIdx.x;
    const int lane = tid & 63, wv = tid >> 6;
    const int l15 = lane & 15, lg = lane >> 4;
    const int wr = wv >> 1, wc = wv & 1;
    const int m0 = blockIdx.y * 128, n0 = blockIdx.x * 128;
    const int srow = lane >> 3, sc_ = lane & 7;

    v4f acc[4][4];
    #pragma unroll
    for (int i = 0; i < 4; ++i)
        #pragma unroll
        for (int j = 0; j < 4; ++j) acc[i][j] = v4f{0.f, 0.f, 0.f, 0.f};

    for (int kt = 0; kt < ktiles; ++kt) {
        const int kb = kt * 64;
        #pragma unroll
        for (int i = 0; i < 4; ++i) {
            int chunk = wv * 4 + i;
            int row = chunk * 8 + srow;
            int csw = (sc_ ^ (row & 7)) << 3;
            gload_lds16(A + (size_t)(m0 + row) * astr + kb + csw, As + chunk * 512);
            gload_lds16(W + (size_t)(n0 + row) * wstr + kb + csw, Bs + chunk * 512);
        }
        __syncthreads();
        #pragma unroll
        for (int kk = 0; kk < 2; ++kk) {
            int sw = (((kk << 2) | lg) ^ (l15 & 7)) << 3;
            v8s af[4], bfv[4];
            #pragma unroll
            for (int mi = 0; mi < 4; ++mi)
                af[mi] = load8(As + (wr * 64 + mi * 16 + l15) * 64 + sw);
            #pragma unroll
            for (int ni = 0; ni < 4; ++ni)
                bfv[ni] = load8(Bs + (wc * 64 + ni * 16 + l15) * 64 + sw);
            #pragma unroll
            for (int mi = 0; mi < 4; ++mi)
                #pragma unroll
                for (int ni = 0; ni < 4; ++ni)
                    acc[mi][ni] = MFMA(af[mi], bfv[ni], acc[mi][ni]);
        }
        __syncthreads();
    }
    #pragma unroll
    for (int mi = 0; mi < 4; ++mi)
        #pragma unroll
        for (int rr = 0; rr < 4; ++rr) {
            int row = m0 + wr * 64 + mi * 16 + lg * 4 + rr;
            #pragma unroll
            for (int ni = 0; ni < 4; ++ni) {
                int col = n0 + wc * 64 + ni * 16 + l15;
                if (outf) outf[(size_t)row * ostr + col] = acc[mi][ni][rr];
                else      outb[(size_t)row * ostr + col] = f2bf(acc[mi][ni][rr]);
            }
        }
}

// ---------------- split-K small GEMM (M=32), sub-mode -----------------------
struct Seg { const u16* a; int astr; const u16* w; int wstr; int k; };

__global__ __launch_bounds__(512) void k_mm(Seg s1, Seg s2, float* __restrict__ outf,
                                            u16* __restrict__ outb, int ostr, int ks,
                                            int sub) {
    const int tid = threadIdx.x;
    const int wv = tid >> 6, lane = tid & 63;
    const int l15 = lane & 15, lg = lane >> 4;
    const int wrow = blockIdx.x * 16 + l15;
    const int k0 = wv * ks, k1 = k0 + ks;
    v4f acc0 = {0.f, 0.f, 0.f, 0.f}, acc1 = {0.f, 0.f, 0.f, 0.f};
    int base = 0;
    auto doseg = [&](const Seg& sg) {
        if (sg.k == 0) return;
        int s0 = k0 > base ? k0 : base;
        int send = base + sg.k;
        int s1e = k1 < send ? k1 : send;
        const u16* wp = sg.w + (size_t)wrow * sg.wstr + 8 * lg;
        const u16* a0p = sg.a + (size_t)l15 * sg.astr + 8 * lg;
        const u16* a1p = sg.a + (size_t)(16 + l15) * sg.astr + 8 * lg;
        #pragma unroll 2
        for (int k = s0; k < s1e; k += 32) {
            int kl = k - base;
            v8s bf = load8(wp + kl);
            v8s af0 = load8(a0p + kl);
            v8s af1 = load8(a1p + kl);
            acc0 = MFMA(af0, bf, acc0);
            acc1 = MFMA(af1, bf, acc1);
        }
        base += sg.k;
    };
    doseg(s1); doseg(s2);

    __shared__ float g[8][32][16];
    #pragma unroll
    for (int r = 0; r < 4; ++r) {
        g[wv][lg * 4 + r][l15] = acc0[r];
        g[wv][16 + lg * 4 + r][l15] = acc1[r];
    }
    __syncthreads();
    {
        int b = tid >> 4, cl = tid & 15;
        float v = 0.f;
        #pragma unroll
        for (int w = 0; w < 8; ++w) v += g[w][b][cl];
        int col = blockIdx.x * 16 + cl;
        size_t idx = (size_t)b * ostr + col;
        if (outb)      outb[idx] = f2bf(v);
        else if (sub)  outf[idx] -= v;
        else           outf[idx] = v;
    }
}

// ---------------- persistent bidirectional encoder ---------------------------
// 128 blocks/dir x 512 thr; 8 output cols/block; weights in REGISTERS.
__global__ __launch_bounds__(512) void k_enc(
    const float* __restrict__ xgF, const float* __restrict__ xgB,
    const u16* __restrict__ whhf, const u16* __restrict__ whhb,
    const float* __restrict__ bihF, const float* __restrict__ bhhF,
    const float* __restrict__ bihB, const float* __restrict__ bhhB,
    u16* __restrict__ hsf, u16* __restrict__ hsb,
    float* __restrict__ cfinal, int* __restrict__ bars) {
    const int blk = blockIdx.x;
    const int dir = blk >> 7, bid = blk & 127;
    const int tid = threadIdx.x;
    const u16* whh = dir ? whhb : whhf;
    const float* xg = dir ? xgB : xgF;
    const float* bih = dir ? bihB : bihF;
    const float* bhh = dir ? bhhB : bhhF;
    u16* hs = dir ? hsb : hsf;
    int* bar = bars + dir * 2048;
    const int j0 = bid * 8;
    __shared__ float glds[8][32][34];
    __shared__ u16 htmp[32][8];
    const int wv = tid >> 6, lane = tid & 63, l15 = lane & 15, lg = lane >> 4;
    // step-invariant weight fragments -> registers (2 row-tiles x 4 kb)
    v8s wreg[2][4];
    #pragma unroll
    for (int rt = 0; rt < 2; ++rt) {
        int wrow = rt * 16 + l15;
        int grow = (wrow >> 3) * H + j0 + (wrow & 7);
        #pragma unroll
        for (int kb = 0; kb < 4; ++kb)
            wreg[rt][kb] = load8(whh + (size_t)grow * H + wv * 128 + kb * 32 + lg * 8);
    }
    const int pb = tid >> 3, pj = tid & 7;
    float creg = 0.f;
    float bsum[4];
    if (tid < 256) {
        #pragma unroll
        for (int gt = 0; gt < 4; ++gt)
            bsum[gt] = bih[gt * H + j0 + pj] + bhh[gt * H + j0 + pj];
    }
    for (int s = 0; s < S; ++s) {
        float xv[4];
        if (tid < 256) {
            int xrow = ((dir ? (S - 1 - s) : s) * 32 + pb) * 4096;
            const float* xr = xg + xrow + j0 + pj;
            #pragma unroll
            for (int gt = 0; gt < 4; ++gt) xv[gt] = xr[gt * H];
        }
        const u16* hp = hs + (size_t)s * (B * H);
        const u16* a0 = hp + (size_t)l15 * H + wv * 128 + 8 * lg;
        const u16* a1 = a0 + (size_t)16 * H;
        v4f acc00 = {0,0,0,0}, acc01 = {0,0,0,0}, acc10 = {0,0,0,0}, acc11 = {0,0,0,0};
        #pragma unroll
        for (int kb = 0; kb < 4; ++kb) {
            v8s af0 = load8(a0 + kb * 32);
            v8s af1 = load8(a1 + kb * 32);
            acc00 = MFMA(af0, wreg[0][kb], acc00);
            acc10 = MFMA(af0, wreg[1][kb], acc10);
            acc01 = MFMA(af1, wreg[0][kb], acc01);
            acc11 = MFMA(af1, wreg[1][kb], acc11);
        }
        #pragma unroll
        for (int r = 0; r < 4; ++r) {
            glds[wv][lg * 4 + r][l15] = acc00[r];
            glds[wv][lg * 4 + r][16 + l15] = acc10[r];
            glds[wv][16 + lg * 4 + r][l15] = acc01[r];
            glds[wv][16 + lg * 4 + r][16 + l15] = acc11[r];
        }
        __syncthreads();
        if (tid < 256) {
            float gv[4];
            #pragma unroll
            for (int gt = 0; gt < 4; ++gt) {
                float v = 0.f;
                #pragma unroll
                for (int w = 0; w < 8; ++w) v += glds[w][pb][gt * 8 + pj];
                gv[gt] = v + xv[gt] + bsum[gt];
            }
            float si = 1.f / (1.f + expf(-gv[0]));
            float sf = 1.f / (1.f + expf(-gv[1]));
            float tg = tanhf(gv[2]);
            float so = 1.f / (1.f + expf(-gv[3]));
            creg = sf * creg + si * tg;
            htmp[pb][pj] = f2bf(so * tanhf(creg));
        }
        __syncthreads();
        if (tid < 128) {
            int rb = tid >> 2, c2 = (tid & 3) * 2;
            unsigned val = (unsigned)htmp[rb][c2] | ((unsigned)htmp[rb][c2 + 1] << 16);
            cstore((unsigned*)(hs + (size_t)(s + 1) * (B * H) + (size_t)rb * H + j0 + c2), val);
        }
        if (s < S - 1) gbar2(bar, bid, 128, s + 1);
    }
    if (tid < 256) cfinal[(size_t)dir * B * H + (size_t)pb * H + j0 + pj] = creg;
}

// ---------------- persistent attention decoder -------------------------------
// 128 blocks x 512 thr; 8 cols/block; fused weights (dwhh+wfuse) in REGISTERS.
__global__ __launch_bounds__(512) void k_dec(
    const float* __restrict__ xgD, const u16* __restrict__ dwhh,
    const u16* __restrict__ wfuse, const float* __restrict__ bih,
    const float* __restrict__ bhh, const float* __restrict__ decc,
    const u16* __restrict__ encab, const u16* __restrict__ ench,
    u16* __restrict__ hc, int* __restrict__ bar) {
    const int bid = blockIdx.x, tid = threadIdx.x;
    const int j0 = bid * 8;
    __shared__ float glds[8][32][34];
    __shared__ float hl[1056];
    __shared__ float sc[64], aw[64];
    __shared__ float cpart[2][256][2];
    __shared__ u16 htmp[32][8];
    const int wv = tid >> 6, lane = tid & 63, l15 = lane & 15, lg = lane >> 4;
    // step-invariant fused weight fragments -> registers (2 row-tiles x 12 kb)
    v8s wreg[2][12];
    #pragma unroll
    for (int rt = 0; rt < 2; ++rt) {
        int wrow = rt * 16 + l15;
        int grow = (wrow >> 3) * H + j0 + (wrow & 7);
        #pragma unroll
        for (int kb = 0; kb < 12; ++kb) {
            int k = wv * 384 + kb * 32 + lg * 8;
            v8s wf = load8(wfuse + (size_t)grow * 3072 + k);
            if (wv * 384 + kb * 32 < 1024) {
                v8s wh = load8(dwhh + (size_t)grow * 1024 + k);
                #pragma unroll
                for (int e = 0; e < 8; ++e)
                    wf[e] = (short)f2bf(bf2f((u16)wf[e]) + bf2f((u16)wh[e]));
            }
            wreg[rt][kb] = wf;
        }
    }
    const int pb = tid >> 3, pj = tid & 7;
    float creg = 0.f;
    float bsum[4];
    if (tid < 256) {
        creg = decc[(size_t)pb * H + j0 + pj];
        #pragma unroll
        for (int gt = 0; gt < 4; ++gt)
            bsum[gt] = bih[gt * H + j0 + pj] + bhh[gt * H + j0 + pj];
    }
    const int ab = bid >> 2, ach = bid & 3;     // attention: batch + 512-dim chunk
    for (int t = 0; t < T; ++t) {
        const u16* hp = hc + (size_t)t * (B * 3072);
        u16* hn = hc + (size_t)(t + 1) * (B * 3072);
        // ---- P1: gates = hc[t] @ Wdec^T + xg
        float xv[4];
        if (tid < 256) {
            const float* xr = xgD + (size_t)(t * 32 + pb) * 4096 + j0 + pj;
            #pragma unroll
            for (int gt = 0; gt < 4; ++gt) xv[gt] = xr[gt * H];
        }
        const u16* a0 = hp + (size_t)l15 * 3072 + wv * 384 + 8 * lg;
        const u16* a1 = a0 + (size_t)16 * 3072;
        v4f acc00 = {0,0,0,0}, acc01 = {0,0,0,0}, acc10 = {0,0,0,0}, acc11 = {0,0,0,0};
        #pragma unroll
        for (int kb = 0; kb < 12; ++kb) {
            v8s af0 = load8(a0 + kb * 32);
            v8s af1 = load8(a1 + kb * 32);
            acc00 = MFMA(af0, wreg[0][kb], acc00);
            acc10 = MFMA(af0, wreg[1][kb], acc10);
            acc01 = MFMA(af1, wreg[0][kb], acc01);
            acc11 = MFMA(af1, wreg[1][kb], acc11);
        }
        #pragma unroll
        for (int r = 0; r < 4; ++r) {
            glds[wv][lg * 4 + r][l15] = acc00[r];
            glds[wv][lg * 4 + r][16 + l15] = acc10[r];
            glds[wv][16 + lg * 4 + r][l15] = acc01[r];
            glds[wv][16 + lg * 4 + r][16 + l15] = acc11[r];
        }
        __syncthreads();
        if (tid < 256) {
            float gv[4];
            #pragma unroll
            for (int gt = 0; gt < 4; ++gt) {
                float v = 0.f;
                #pragma unroll
                for (int w = 0; w < 8; ++w) v += glds[w][pb][gt * 8 + pj];
                gv[gt] = v + xv[gt] + bsum[gt];
            }
            float si = 1.f / (1.f + expf(-gv[0]));
            float sf = 1.f / (1.f + expf(-gv[1]));
            float tg = tanhf(gv[2]);
            float so = 1.f / (1.f + expf(-gv[3]));
            creg = sf * creg + si * tg;
            htmp[pb][pj] = f2bf(so * tanhf(creg));
        }
        __syncthreads();
        if (tid < 128) {
            int rb = tid >> 2, c2 = (tid & 3) * 2;
            unsigned val = (unsigned)htmp[rb][c2] | ((unsigned)htmp[rb][c2 + 1] << 16);
            cstore((unsigned*)(hn + (size_t)rb * 3072 + j0 + c2), val);
        }
        gbar2(bar, bid, 128, 2 * t + 1);
        // ---- P2: attention (b = bid>>2, 512-dim chunk = bid&3)
        {
            const u16* hb = hn + (size_t)ab * 3072;
            for (int i = tid; i < 1024; i += 512)
                hl[((i >> 7) * 132) + (i & 127)] = bf2f(hb[i]);
            __syncthreads();
            {
                int si2 = tid >> 3, pt = tid & 7;
                const u16* ap = encab + ((size_t)(ab * 64 + si2)) * 1024 + pt * 128;
                const float* hq = hl + pt * 132;
                float ps = 0.f;
                #pragma unroll
                for (int x = 0; x < 16; ++x) {
                    v8s v = load8(ap + x * 8);
                    #pragma unroll
                    for (int e = 0; e < 8; ++e) ps += bf2f((u16)v[e]) * hq[x * 8 + e];
                }
                ps += __shfl_xor(ps, 1); ps += __shfl_xor(ps, 2); ps += __shfl_xor(ps, 4);
                if (pt == 0) sc[si2] = ps;
            }
            __syncthreads();
            if (tid < 64) {
                float v = sc[tid];
                float m = v;
                #pragma unroll
                for (int o = 32; o; o >>= 1) m = fmaxf(m, __shfl_xor(m, o));
                float e = expf(v - m), sum = e;
                #pragma unroll
                for (int o = 32; o; o >>= 1) sum += __shfl_xor(sum, o);
                aw[tid] = e / sum;
            }
            __syncthreads();
            {   // ctx: 2-way s2 split x 256 d-pairs (512 dims)
                int q = tid >> 8, dp = tid & 255;
                int d = ach * 512 + dp * 2;
                const u16* ep = ench + (size_t)ab * S * 2048 + (size_t)(q * 32) * 2048 + d;
                float c0 = 0.f, c1 = 0.f;
                #pragma unroll 8
                for (int s2 = 0; s2 < 32; ++s2) {
                    unsigned uv = *reinterpret_cast<const unsigned*>(ep);
                    float w = aw[q * 32 + s2];
                    c0 += w * bf2f((u16)(uv & 0xFFFF));
                    c1 += w * bf2f((u16)(uv >> 16));
                    ep += 2048;
                }
                cpart[q][dp][0] = c0;
                cpart[q][dp][1] = c1;
            }
            __syncthreads();
            if (tid < 256) {
                float c0 = cpart[0][tid][0] + cpart[1][tid][0];
                float c1 = cpart[0][tid][1] + cpart[1][tid][1];
                unsigned ov = ((unsigned)f2bf(c1) << 16) | f2bf(c0);
                cstore((unsigned*)(hn + (size_t)ab * 3072 + 1024 + ach * 512 + tid * 2), ov);
            }
        }
        if (t < T - 1) gbar2(bar, bid, 128, 2 * t + 2);
    }
}

// ---------------- tiled projection GEMM + fused softmax partials ------------
__global__ __launch_bounds__(512) void k_proj(const u16* __restrict__ A,
                                              const u16* __restrict__ W,
                                              const int* __restrict__ tgt,
                                              float* __restrict__ pmax,
                                              float* __restrict__ psum,
                                              float* __restrict__ pgold) {
    __shared__ __align__(16) u16 As[256 * 64];
    __shared__ __align__(16) u16 Bs[128 * 64];
    __shared__ float red[256][2][3];
    const int tid = threadIdx.x;
    const int lane = tid & 63, wv = tid >> 6;
    const int l15 = lane & 15, lg = lane >> 4;
    const int wr = wv >> 1, wc = wv & 1;
    int orig = blockIdx.x;
    int xcd = orig & 7, loc = orig >> 3;
    int wgid = (xcd < 4 ? xcd * 188 : 752 + (xcd - 4) * 187) + loc;
    int nt = wgid / 6, mt = wgid % 6;
    const int m0 = mt * 256, n0 = nt * 128;
    const int srow = lane >> 3, sc_ = lane & 7;

    v4f acc[4][4];
    #pragma unroll
    for (int i = 0; i < 4; ++i)
        #pragma unroll
        for (int j = 0; j < 4; ++j) acc[i][j] = v4f{0.f, 0.f, 0.f, 0.f};

    for (int kt = 0; kt < 16; ++kt) {
        const int kb = kt * 64;
        #pragma unroll
        for (int i = 0; i < 4; ++i) {
            int chunk = wv * 4 + i;
            int row = chunk * 8 + srow;
            int csw = (sc_ ^ (row & 7)) << 3;
            gload_lds16(A + (size_t)(m0 + row) * 1024 + kb + csw, As + chunk * 512);
        }
        #pragma unroll
        for (int i = 0; i < 2; ++i) {
            int chunk = wv * 2 + i;
            int row = chunk * 8 + srow;
            int csw = (sc_ ^ (row & 7)) << 3;
            gload_lds16(W + (size_t)(n0 + row) * 1024 + kb + csw, Bs + chunk * 512);
        }
        __syncthreads();
        #pragma unroll
        for (int kk = 0; kk < 2; ++kk) {
            int sw = (((kk << 2) | lg) ^ (l15 & 7)) << 3;
            v8s af[4], bfv[4];
            #pragma unroll
            for (int mi = 0; mi < 4; ++mi)
                af[mi] = load8(As + (wr * 64 + mi * 16 + l15) * 64 + sw);
            #pragma unroll
            for (int ni = 0; ni < 4; ++ni)
                bfv[ni] = load8(Bs + (wc * 64 + ni * 16 + l15) * 64 + sw);
            #pragma unroll
            for (int mi = 0; mi < 4; ++mi)
                #pragma unroll
                for (int ni = 0; ni < 4; ++ni)
                    acc[mi][ni] = MFMA(af[mi], bfv[ni], acc[mi][ni]);
        }
        __syncthreads();
    }
    #pragma unroll
    for (int mi = 0; mi < 4; ++mi) {
        #pragma unroll
        for (int rr = 0; rr < 4; ++rr) {
            int lrow = wr * 64 + mi * 16 + lg * 4 + rr;
            int grow = m0 + lrow;
            float vmax = -1e30f;
            #pragma unroll
            for (int ni = 0; ni < 4; ++ni) vmax = fmaxf(vmax, acc[mi][ni][rr]);
            #pragma unroll
            for (int x = 1; x < 16; x <<= 1) vmax = fmaxf(vmax, __shfl_xor(vmax, x));
            float se = 0.f;
            #pragma unroll
            for (int ni = 0; ni < 4; ++ni) se += expf(acc[mi][ni][rr] - vmax);
            #pragma unroll
            for (int x = 1; x < 16; x <<= 1) se += __shfl_xor(se, x);
            int t = grow >> 5, b = grow & 31;
            int g = (grow < MROWS) ? tgt[b * T + t + 1] : -1;
            float gv = 0.f;
            #pragma unroll
            for (int ni = 0; ni < 4; ++ni) {
                int col = n0 + wc * 64 + ni * 16 + l15;
                if (col == g) gv = acc[mi][ni][rr];
            }
            #pragma unroll
            for (int x = 1; x < 16; x <<= 1) gv += __shfl_xor(gv, x);
            if (l15 == 0) {
                red[lrow][wc][0] = vmax;
                red[lrow][wc][1] = se;
                red[lrow][wc][2] = gv;
            }
        }
    }
    __syncthreads();
    if (tid < 256) {
        int grow = m0 + tid;
        if (grow < MROWS) {
            float ma = red[tid][0][0], mb = red[tid][1][0];
            float M = fmaxf(ma, mb);
            float Sv = red[tid][0][1] * expf(ma - M) + red[tid][1][1] * expf(mb - M);
            float G = red[tid][0][2] + red[tid][1][2];
            size_t idx = (size_t)grow * NCH + nt;
            pmax[idx] = M; psum[idx] = Sv; pgold[idx] = G;
        }
    }
}

// ---------------- combine chunks -> logP[row] ----------------
__global__ __launch_bounds__(256) void k_lse(const float* __restrict__ pmax,
                                             const float* __restrict__ psum,
                                             const float* __restrict__ pgold,
                                             float* __restrict__ logP) {
    int item = blockIdx.x * 4 + (threadIdx.x >> 6);
    int lane = threadIdx.x & 63;
    if (item >= MROWS) return;
    float m = -1e30f, g = 0.f;
    for (int c = lane; c < NCH; c += 64) {
        size_t idx = (size_t)item * NCH + c;
        m = fmaxf(m, pmax[idx]);
        g += pgold[idx];
    }
    for (int o = 32; o; o >>= 1) m = fmaxf(m, __shfl_xor(m, o));
    float s = 0.f;
    for (int c = lane; c < NCH; c += 64) {
        size_t idx = (size_t)item * NCH + c;
        s += psum[idx] * expf(pmax[idx] - m);
    }
    for (int o = 32; o; o >>= 1) { s += __shfl_xor(s, o); g += __shfl_xor(g, o); }
    if (lane == 0) logP[item] = g - (m + logf(s));
}

__global__ __launch_bounds__(64) void k_final(const float* __restrict__ logP,
                                              float* __restrict__ out) {
    int b = threadIdx.x;
    if (b < 32) {
        float s = 0.f;
        for (int t = 0; t < TP; ++t) s += logP[t * 32 + b];
        out[b] = s;
    }
}

// ================= host =================
extern "C" void kernel_launch(void* const* d_in, const int* in_sizes, int n_in,
                              void* d_out, int out_size, void* d_ws, size_t ws_size,
                              hipStream_t stream) {
    const int*   seq_in  = (const int*)d_in[0];
    const int*   seq_tgt = (const int*)d_in[1];
    const float* src_emb = (const float*)d_in[2];
    const float* tgt_emb = (const float*)d_in[3];
    const float* eWihF = (const float*)d_in[4];
    const float* eWhhF = (const float*)d_in[5];
    const float* eBihF = (const float*)d_in[6];
    const float* eBhhF = (const float*)d_in[7];
    const float* eWihB = (const float*)d_in[8];
    const float* eWhhB = (const float*)d_in[9];
    const float* eBihB = (const float*)d_in[10];
    const float* eBhhB = (const float*)d_in[11];
    const float* dWih  = (const float*)d_in[12];
    const float* dWhh  = (const float*)d_in[13];
    const float* dBih  = (const float*)d_in[14];
    const float* dBhh  = (const float*)d_in[15];
    const float* WinH  = (const float*)d_in[16];
    const float* WinC  = (const float*)d_in[17];
    const float* Watt  = (const float*)d_in[18];
    const float* Wcomb = (const float*)d_in[19];
    const float* Wproj = (const float*)d_in[20];

    char* ws = (char*)d_ws;
    size_t off = 0;
    auto alloc = [&](size_t bytes) -> char* {
        off = (off + 255) & ~(size_t)255;
        char* p = ws + off;
        off += bytes;
        return p;
    };
    const size_t G4 = 4 * (size_t)H;
    const size_t slot = (size_t)B * H;
    // bf16 weights
    u16* wihf = (u16*)alloc(G4 * E * 2);
    u16* whhf = (u16*)alloc(G4 * H * 2);
    u16* wihb = (u16*)alloc(G4 * E * 2);
    u16* whhb = (u16*)alloc(G4 * H * 2);
    u16* dwih = (u16*)alloc(G4 * (E + H) * 2);
    u16* dwhh = (u16*)alloc(G4 * H * 2);
    u16* winh = (u16*)alloc((size_t)H * 2 * H * 2);
    u16* winc = (u16*)alloc((size_t)H * 2 * H * 2);
    u16* watt = (u16*)alloc((size_t)H * 2 * H * 2);
    u16* wcmb = (u16*)alloc((size_t)H * 3 * H * 2);
    u16* wprj = (u16*)alloc((size_t)V * H * 2);
    u16* wcmbT = (u16*)alloc((size_t)3 * H * H * 2);
    u16* wfuse = (u16*)alloc((size_t)G4 * 3 * H * 2);
    // bf16 activations
    u16* xsrc  = (u16*)alloc((size_t)S * B * E * 2);
    u16* xtgt  = (u16*)alloc((size_t)T * B * E * 2);
    u16* hsf   = (u16*)alloc((size_t)(S + 1) * slot * 2);
    u16* hsb   = (u16*)alloc((size_t)(S + 1) * slot * 2);
    u16* ench  = (u16*)alloc((size_t)B * S * 2 * H * 2);
    u16* encab = (u16*)alloc((size_t)B * S * H * 2);
    u16* hc    = (u16*)alloc((size_t)(T + 1) * B * 3072 * 2);
    u16* outsb = (u16*)alloc((size_t)(T * B) * H * 2);
    u16* lcbf  = (u16*)alloc(2 * slot * 2);
    // f32 buffers
    float* xgF  = (float*)alloc((size_t)S * B * G4 * 4);
    float* xgB  = (float*)alloc((size_t)S * B * G4 * 4);
    float* xgD  = (float*)alloc((size_t)T * B * G4 * 4);
    float* cf2  = (float*)alloc(2 * slot * 4);
    float* decc = (float*)alloc(slot * 4);
    float* pmax  = (float*)alloc((size_t)MROWS * NCH * 4);
    float* psum  = (float*)alloc((size_t)MROWS * NCH * 4);
    float* pgold = (float*)alloc((size_t)MROWS * NCH * 4);
    float* logP  = (float*)alloc((size_t)MROWS * 4);
    int* bars = (int*)alloc(3 * 2048 * 4);
    (void)ws_size; (void)in_sizes; (void)n_in; (void)out_size;

    hipMemsetAsync(hsf, 0, slot * 2, stream);
    hipMemsetAsync(hsb, 0, slot * 2, stream);
    hipMemsetAsync(hc, 0, (size_t)B * 3072 * 2, stream);   // hc[0] (ctx part = 0)
    hipMemsetAsync(bars, 0, 3 * 2048 * 4, stream);

    // merged weight conversions (11 segments, one launch)
    {
        CvtD d;
        const float* srcs[11] = {eWihF, eWhhF, eWihB, eWhhB, dWih, dWhh,
                                 WinH, WinC, Watt, Wcomb, Wproj};
        u16* dsts[11] = {wihf, whhf, wihb, whhb, dwih, dwhh,
                         winh, winc, watt, wcmb, wprj};
        size_t ns[11] = {G4 * E, G4 * H, G4 * E, G4 * H, G4 * (E + H), G4 * H,
                         (size_t)H * 2 * H, (size_t)H * 2 * H, (size_t)H * 2 * H,
                         (size_t)H * 3 * H, (size_t)V * H};
        int blk = 0;
        for (int i = 0; i < 11; ++i) {
            d.src[i] = srcs[i];
            d.dst[i] = dsts[i];
            d.n4[i] = (int)(ns[i] / 4);
            d.start[i] = blk;
            blk += (d.n4[i] + 255) / 256;
        }
        d.start[11] = blk;
        k_cvtm<<<dim3(blk), dim3(256), 0, stream>>>(d);
    }

    k_embed<<<dim3((S * B * (E / 4) + 255) / 256), dim3(256), 0, stream>>>(
        seq_in, S, S, src_emb, xsrc);
    k_embed<<<dim3((T * B * (E / 4) + 255) / 256), dim3(256), 0, stream>>>(
        seq_tgt, T, T, tgt_emb, xtgt);

    k_transp<<<dim3(3 * H / 64, H / 64), dim3(256), 0, stream>>>(wcmb, wcmbT, H, 3 * H);

    // prefolded input gates: xg = x @ Wih^T (f32)
    k_tile<<<dim3(32, 16), dim3(256), 0, stream>>>(xsrc, E, wihf, E, xgF, nullptr, 4096, 8);
    k_tile<<<dim3(32, 16), dim3(256), 0, stream>>>(xsrc, E, wihb, E, xgB, nullptr, 4096, 8);
    k_tile<<<dim3(32, 12), dim3(256), 0, stream>>>(xtgt, E, dwih, E + H, xgD, nullptr, 4096, 8);
    k_tile<<<dim3(24, 32), dim3(256), 0, stream>>>(dwih + E, E + H, wcmbT, H,
                                                   nullptr, wfuse, 3 * H, 16);

    // ---------- persistent bidirectional encoder ----------
    k_enc<<<dim3(256), dim3(512), 0, stream>>>(xgF, xgB, whhf, whhb,
                                               eBihF, eBhhF, eBihB, eBhhB,
                                               hsf, hsb, cf2, bars);

    k_ench<<<dim3(B * S * (2 * H / 8) / 256), dim3(256), 0, stream>>>(hsf, hsb, ench);
    k_tile<<<dim3(8, 16), dim3(256), 0, stream>>>(ench, 2 * H, watt, 2 * H,
                                                  nullptr, encab, H, 32);
    {
        int n4 = (int)(2 * slot / 4);
        k_cvt<<<dim3((n4 + 255) / 256), dim3(256), 0, stream>>>(cf2, lcbf, n4);
    }

    // decoder init: dec_h0 directly into hc[0] (bf16, stride 3072); c0; xgD corr
    {
        Seg a1{hsf + (size_t)S * slot, H, winh, 2 * H, H};
        Seg a2{hsb + (size_t)S * slot, H, winh + H, 2 * H, H};
        k_mm<<<dim3(H / 16), dim3(512), 0, stream>>>(a1, a2, nullptr, hc, 3072,
                                                     2 * H / 8, 0);
        Seg c1{lcbf, H, winc, 2 * H, H};
        Seg c2{lcbf + slot, H, winc + H, 2 * H, H};
        k_mm<<<dim3(H / 16), dim3(512), 0, stream>>>(c1, c2, decc, nullptr, H,
                                                     2 * H / 8, 0);
        // xgD[0] -= hc[0] @ Wfuse_h^T   (sub-mode)
        Seg f1{hc, 3072, wfuse, 3 * H, H};
        Seg f0{nullptr, 0, nullptr, 0, 0};
        k_mm<<<dim3(G4 / 16), dim3(512), 0, stream>>>(f1, f0, xgD, nullptr, 4096,
                                                      H / 8, 1);
    }

    // ---------- persistent attention decoder ----------
    k_dec<<<dim3(128), dim3(512), 0, stream>>>(xgD, dwhh, wfuse, dBih, dBhh, decc,
                                               encab, ench, hc, bars + 4096);

    // outs = hc[1..48] @ Wcomb^T (bf16)
    k_tile<<<dim3(8, 12), dim3(256), 0, stream>>>(hc + B * 3072, 3 * H, wcmb, 3 * H,
                                                  nullptr, outsb, H, 48);

    // ---------- vocab projection + log-softmax ----------
    k_proj<<<dim3(1500), dim3(512), 0, stream>>>(outsb, wprj, seq_tgt, pmax, psum, pgold);
    k_lse<<<dim3((MROWS + 3) / 4), dim3(256), 0, stream>>>(pmax, psum, pgold, logP);
    k_final<<<dim3(1), dim3(64), 0, stream>>>(logP, (float*)d_out);
}

// Round 13
// 1419.939 us; speedup vs baseline: 1.5555x; 1.5555x over previous
//
#include <hip/hip_runtime.h>

typedef short v8s __attribute__((ext_vector_type(8)));
typedef float v4f __attribute__((ext_vector_type(4)));
typedef unsigned short u16;

#define DI __device__ __forceinline__
#define MFMA(a, b, c) __builtin_amdgcn_mfma_f32_16x16x32_bf16(a, b, c, 0, 0, 0)

constexpr int B = 32, S = 64, T = 48, E = 512, H = 1024, V = 32000;
constexpr int TP = T - 1;        // 47 prediction steps
constexpr int MROWS = TP * B;    // 1504 valid proj rows
constexpr int NCH = 250;         // 32000 / 128 vocab chunks

DI u16 f2bf(float f) {
    unsigned u = __float_as_uint(f);
    unsigned r = (u + 0x7FFFu + ((u >> 16) & 1u)) >> 16;
    return (u16)r;
}
DI float bf2f(u16 h) { return __uint_as_float(((unsigned)h) << 16); }
DI v8s load8(const u16* p) { return *reinterpret_cast<const v8s*>(p); }

typedef __attribute__((address_space(1))) const unsigned int gu32;
typedef __attribute__((address_space(3))) unsigned int lu32;
DI void gload_lds16(const u16* g, u16* l) {
    __builtin_amdgcn_global_load_lds((gu32*)g, (lu32*)l, 16, 0, 0);
}

// coherence-point u32 store (bypasses private L2; visible to all XCDs)
DI void cstore(unsigned* p, unsigned v) {
    __hip_atomic_store(p, v, __ATOMIC_RELAXED, __HIP_MEMORY_SCOPE_AGENT);
}
DI int cload(const int* p) {
    return __hip_atomic_load(p, __ATOMIC_RELAXED, __HIP_MEMORY_SCOPE_AGENT);
}

// ---------------- root-scan grid barrier (R5/R9 proven) ----------------------
DI void gbar2(int* bar, int bid, int nblk, int v) {
    __syncthreads();
    if (bid == 0) {
        int t = threadIdx.x;
        if (t > 0 && t < nblk) {
            while (cload(bar + 16 + t * 4) < v) __builtin_amdgcn_s_sleep(1);
        }
        __syncthreads();
        if (t == 0)
            __hip_atomic_store(bar, v, __ATOMIC_RELAXED, __HIP_MEMORY_SCOPE_AGENT);
    } else {
        if (threadIdx.x == 0) {
            __hip_atomic_store(bar + 16 + bid * 4, v, __ATOMIC_RELAXED,
                               __HIP_MEMORY_SCOPE_AGENT);
            while (cload(bar) < v) __builtin_amdgcn_s_sleep(2);
        }
        __syncthreads();
    }
}

// ---------------- elementwise conversion f32 -> bf16 ----------------
__global__ __launch_bounds__(256) void k_cvt(const float* __restrict__ s,
                                             u16* __restrict__ d, int n4) {
    int i = blockIdx.x * 256 + threadIdx.x;
    if (i >= n4) return;
    float4 v = reinterpret_cast<const float4*>(s)[i];
    ushort4 o;
    o.x = f2bf(v.x); o.y = f2bf(v.y); o.z = f2bf(v.z); o.w = f2bf(v.w);
    reinterpret_cast<ushort4*>(d)[i] = o;
}

// ---------------- merged multi-segment conversion ----------------
struct CvtD {
    const float* src[11];
    u16* dst[11];
    int n4[11];
    int start[12];
};
__global__ __launch_bounds__(256) void k_cvtm(CvtD d) {
    int blk = blockIdx.x;
    int seg = 0;
    #pragma unroll
    for (int q = 0; q < 11; ++q)
        if (blk >= d.start[q + 1]) seg = q + 1;
    int i = (blk - d.start[seg]) * 256 + threadIdx.x;
    if (i >= d.n4[seg]) return;
    float4 v = reinterpret_cast<const float4*>(d.src[seg])[i];
    ushort4 o;
    o.x = f2bf(v.x); o.y = f2bf(v.y); o.z = f2bf(v.z); o.w = f2bf(v.w);
    reinterpret_cast<ushort4*>(d.dst[seg])[i] = o;
}

// ---------------- embedding gather ----------------
__global__ __launch_bounds__(256) void k_embed(const int* __restrict__ seq, int seqstr,
                                               int nsteps, const float* __restrict__ emb,
                                               u16* __restrict__ out) {
    int i = blockIdx.x * 256 + threadIdx.x;
    int total = nsteps * B * (E / 4);
    if (i >= total) return;
    int q = i & 127;
    int sb = i >> 7;
    int b = sb & 31;
    int s = sb >> 5;
    int tok = seq[b * seqstr + s];
    float4 v = reinterpret_cast<const float4*>(emb + (size_t)tok * E)[q];
    ushort4 o;
    o.x = f2bf(v.x); o.y = f2bf(v.y); o.z = f2bf(v.z); o.w = f2bf(v.w);
    reinterpret_cast<ushort4*>(out + ((size_t)(s * B + b)) * E)[q] = o;
}

// ---------------- build ench[b][s][2H] from hsf/hsb ----------------
__global__ __launch_bounds__(256) void k_ench(const u16* __restrict__ hsf,
                                              const u16* __restrict__ hsb,
                                              u16* __restrict__ ench) {
    int id = blockIdx.x * 256 + threadIdx.x;
    int d8 = id & 255; int s = (id >> 8) & 63; int b = id >> 14;
    int d0 = d8 * 8;
    const u16* src = (d0 < H) ? hsf + (((size_t)(s + 1) * B + b)) * H + d0
                              : hsb + (((size_t)(S - s) * B + b)) * H + (d0 - H);
    *reinterpret_cast<v8s*>(ench + ((size_t)b * S + s) * 2 * H + d0) = load8(src);
}

// ---------------- transpose: out[n][k] = in[k][n], in K x N -----------------
__global__ __launch_bounds__(256) void k_transp(const u16* __restrict__ in,
                                                u16* __restrict__ out, int K, int N) {
    __shared__ u16 t[64][72];
    int nt = blockIdx.x * 64, kt = blockIdx.y * 64;
    int tid = threadIdx.x;
    int r = tid >> 2, cq = (tid & 3) * 16;
    v8s v0 = load8(in + (size_t)(kt + r) * N + nt + cq);
    v8s v1 = load8(in + (size_t)(kt + r) * N + nt + cq + 8);
    #pragma unroll
    for (int e = 0; e < 8; ++e) { t[r][cq + e] = (u16)v0[e]; t[r][cq + 8 + e] = (u16)v1[e]; }
    __syncthreads();
    v8s o0, o1;
    #pragma unroll
    for (int e = 0; e < 8; ++e) { o0[e] = (short)t[cq + e][r]; o1[e] = (short)t[cq + 8 + e][r]; }
    *reinterpret_cast<v8s*>(out + (size_t)(nt + r) * K + kt + cq) = o0;
    *reinterpret_cast<v8s*>(out + (size_t)(nt + r) * K + kt + cq + 8) = o1;
}

// ---------------- generic tiled GEMM: out = A @ W^T (128x128 tile) ----------
__global__ __launch_bounds__(256) void k_tile(const u16* __restrict__ A, int astr,
                                              const u16* __restrict__ W, int wstr,
                                              float* __restrict__ outf,
                                              u16* __restrict__ outb, int ostr,
                                              int ktiles) {
    __shared__ __align__(16) u16 As[128 * 64];
    __shared__ __align__(16) u16 Bs[128 * 64];
    const int tid = threadIdx.x;
    const int lane = tid & 63, wv = tid >> 6;
    const int l15 = lane & 15, lg = lane >> 4;
    const int wr = wv >> 1, wc = wv & 1;
    const int m0 = blockIdx.y * 128, n0 = blockIdx.x * 128;
    const int srow = lane >> 3, sc_ = lane & 7;

    v4f acc[4][4];
    #pragma unroll
    for (int i = 0; i < 4; ++i)
        #pragma unroll
        for (int j = 0; j < 4; ++j) acc[i][j] = v4f{0.f, 0.f, 0.f, 0.f};

    for (int kt = 0; kt < ktiles; ++kt) {
        const int kb = kt * 64;
        #pragma unroll
        for (int i = 0; i < 4; ++i) {
            int chunk = wv * 4 + i;
            int row = chunk * 8 + srow;
            int csw = (sc_ ^ (row & 7)) << 3;
            gload_lds16(A + (size_t)(m0 + row) * astr + kb + csw, As + chunk * 512);
            gload_lds16(W + (size_t)(n0 + row) * wstr + kb + csw, Bs + chunk * 512);
        }
        __syncthreads();
        #pragma unroll
        for (int kk = 0; kk < 2; ++kk) {
            int sw = (((kk << 2) | lg) ^ (l15 & 7)) << 3;
            v8s af[4], bfv[4];
            #pragma unroll
            for (int mi = 0; mi < 4; ++mi)
                af[mi] = load8(As + (wr * 64 + mi * 16 + l15) * 64 + sw);
            #pragma unroll
            for (int ni = 0; ni < 4; ++ni)
                bfv[ni] = load8(Bs + (wc * 64 + ni * 16 + l15) * 64 + sw);
            #pragma unroll
            for (int mi = 0; mi < 4; ++mi)
                #pragma unroll
                for (int ni = 0; ni < 4; ++ni)
                    acc[mi][ni] = MFMA(af[mi], bfv[ni], acc[mi][ni]);
        }
        __syncthreads();
    }
    #pragma unroll
    for (int mi = 0; mi < 4; ++mi)
        #pragma unroll
        for (int rr = 0; rr < 4; ++rr) {
            int row = m0 + wr * 64 + mi * 16 + lg * 4 + rr;
            #pragma unroll
            for (int ni = 0; ni < 4; ++ni) {
                int col = n0 + wc * 64 + ni * 16 + l15;
                if (outf) outf[(size_t)row * ostr + col] = acc[mi][ni][rr];
                else      outb[(size_t)row * ostr + col] = f2bf(acc[mi][ni][rr]);
            }
        }
}

// ---------------- split-K small GEMM (M=32), sub-mode -----------------------
struct Seg { const u16* a; int astr; const u16* w; int wstr; int k; };

__global__ __launch_bounds__(512) void k_mm(Seg s1, Seg s2, float* __restrict__ outf,
                                            u16* __restrict__ outb, int ostr, int ks,
                                            int sub) {
    const int tid = threadIdx.x;
    const int wv = tid >> 6, lane = tid & 63;
    const int l15 = lane & 15, lg = lane >> 4;
    const int wrow = blockIdx.x * 16 + l15;
    const int k0 = wv * ks, k1 = k0 + ks;
    v4f acc0 = {0.f, 0.f, 0.f, 0.f}, acc1 = {0.f, 0.f, 0.f, 0.f};
    int base = 0;
    auto doseg = [&](const Seg& sg) {
        if (sg.k == 0) return;
        int s0 = k0 > base ? k0 : base;
        int send = base + sg.k;
        int s1e = k1 < send ? k1 : send;
        const u16* wp = sg.w + (size_t)wrow * sg.wstr + 8 * lg;
        const u16* a0p = sg.a + (size_t)l15 * sg.astr + 8 * lg;
        const u16* a1p = sg.a + (size_t)(16 + l15) * sg.astr + 8 * lg;
        #pragma unroll 2
        for (int k = s0; k < s1e; k += 32) {
            int kl = k - base;
            v8s bf = load8(wp + kl);
            v8s af0 = load8(a0p + kl);
            v8s af1 = load8(a1p + kl);
            acc0 = MFMA(af0, bf, acc0);
            acc1 = MFMA(af1, bf, acc1);
        }
        base += sg.k;
    };
    doseg(s1); doseg(s2);

    __shared__ float g[8][32][16];
    #pragma unroll
    for (int r = 0; r < 4; ++r) {
        g[wv][lg * 4 + r][l15] = acc0[r];
        g[wv][16 + lg * 4 + r][l15] = acc1[r];
    }
    __syncthreads();
    {
        int b = tid >> 4, cl = tid & 15;
        float v = 0.f;
        #pragma unroll
        for (int w = 0; w < 8; ++w) v += g[w][b][cl];
        int col = blockIdx.x * 16 + cl;
        size_t idx = (size_t)b * ostr + col;
        if (outb)      outb[idx] = f2bf(v);
        else if (sub)  outf[idx] -= v;
        else           outf[idx] = v;
    }
}

// ---------------- persistent bidirectional encoder (512 thr, K/8 per wave) --
__global__ __launch_bounds__(512) void k_enc(
    const float* __restrict__ xgF, const float* __restrict__ xgB,
    const u16* __restrict__ whhf, const u16* __restrict__ whhb,
    const float* __restrict__ bihF, const float* __restrict__ bhhF,
    const float* __restrict__ bihB, const float* __restrict__ bhhB,
    u16* __restrict__ hsf, u16* __restrict__ hsb,
    float* __restrict__ cfinal, int* __restrict__ bars) {
    const int blk = blockIdx.x;
    const int dir = blk >> 8, bid = blk & 255;
    const int tid = threadIdx.x;
    const u16* whh = dir ? whhb : whhf;
    const float* xg = dir ? xgB : xgF;
    const float* bih = dir ? bihB : bihF;
    const float* bhh = dir ? bhhB : bhhF;
    u16* hs = dir ? hsb : hsf;
    int* bar = bars + dir * 2048;
    const int j0 = bid * 4;
    __shared__ u16 wlds[16 * 1024];
    __shared__ float glds[8][32][16];
    __shared__ u16 htmp[32][4];
    {   // 512-thread weight load, swizzled layout
        int r = tid >> 5, kc = tid & 31;
        int gate = r >> 2, jl = r & 3;
        const u16* src = whh + (size_t)(gate * H + j0 + jl) * H;
        #pragma unroll
        for (int i = 0; i < 4; ++i) {
            int c = kc + 32 * i;
            v8s v = load8(src + c * 8);
            *reinterpret_cast<v8s*>(wlds + r * 1024 + ((c ^ (r & 7)) * 8)) = v;
        }
    }
    float creg = 0.f;
    const int pb = tid >> 2, pj = tid & 3;
    float bsum[4];
    if (tid < 128) {
        #pragma unroll
        for (int gt = 0; gt < 4; ++gt)
            bsum[gt] = bih[gt * H + j0 + pj] + bhh[gt * H + j0 + pj];
    }
    __syncthreads();
    const int wv = tid >> 6, lane = tid & 63, l15 = lane & 15, lg = lane >> 4;
    for (int s = 0; s < S; ++s) {
        float xv[4];
        if (tid < 128) {
            int xrow = ((dir ? (S - 1 - s) : s) * 32 + pb) * 4096;
            const float* xr = xg + xrow + j0 + pj;
            #pragma unroll
            for (int gt = 0; gt < 4; ++gt) xv[gt] = xr[gt * H];
        }
        const u16* hp = hs + (size_t)s * (B * H);
        const u16* a0 = hp + (size_t)l15 * H + wv * 128 + 8 * lg;
        const u16* a1 = a0 + (size_t)16 * H;
        v4f acc0 = {0.f, 0.f, 0.f, 0.f}, acc1 = {0.f, 0.f, 0.f, 0.f};
        #pragma unroll
        for (int kb = 0; kb < 4; ++kb) {
            int c = wv * 16 + kb * 4 + lg;
            v8s bf = load8(wlds + l15 * 1024 + ((c ^ (l15 & 7)) * 8));
            v8s af0 = load8(a0 + kb * 32);
            v8s af1 = load8(a1 + kb * 32);
            acc0 = MFMA(af0, bf, acc0);
            acc1 = MFMA(af1, bf, acc1);
        }
        #pragma unroll
        for (int r = 0; r < 4; ++r) {
            glds[wv][lg * 4 + r][l15] = acc0[r];
            glds[wv][16 + lg * 4 + r][l15] = acc1[r];
        }
        __syncthreads();
        if (tid < 128) {
            float gv[4];
            #pragma unroll
            for (int gt = 0; gt < 4; ++gt) {
                float v = 0.f;
                #pragma unroll
                for (int w = 0; w < 8; ++w) v += glds[w][pb][gt * 4 + pj];
                gv[gt] = v + xv[gt] + bsum[gt];
            }
            float si = 1.f / (1.f + expf(-gv[0]));
            float sf = 1.f / (1.f + expf(-gv[1]));
            float tg = tanhf(gv[2]);
            float so = 1.f / (1.f + expf(-gv[3]));
            creg = sf * creg + si * tg;
            htmp[pb][pj] = f2bf(so * tanhf(creg));
        }
        __syncthreads();
        if (tid < 64) {
            int rb = tid >> 1, c2 = (tid & 1) * 2;
            unsigned val = (unsigned)htmp[rb][c2] | ((unsigned)htmp[rb][c2 + 1] << 16);
            cstore((unsigned*)(hs + (size_t)(s + 1) * (B * H) + (size_t)rb * H + j0 + c2), val);
        }
        if (s < S - 1) gbar2(bar, bid, 256, s + 1);
    }
    if (tid < 128) cfinal[(size_t)dir * B * H + (size_t)pb * H + j0 + pj] = creg;
}

// ---------------- persistent attention decoder ----------------
__global__ __launch_bounds__(512) void k_dec(
    const float* __restrict__ xgD, const u16* __restrict__ dwhh,
    const u16* __restrict__ wfuse, const float* __restrict__ bih,
    const float* __restrict__ bhh, const float* __restrict__ decc,
    const u16* __restrict__ encab, const u16* __restrict__ ench,
    u16* __restrict__ hc, int* __restrict__ bar) {
    const int bid = blockIdx.x, tid = threadIdx.x;
    const int j0 = bid * 4;
    __shared__ u16 wlds[16 * 3072];
    __shared__ float glds[8][32][16];
    __shared__ float hl[1056];               // 132-stride padded
    __shared__ float sc[64], aw[64];
    __shared__ float cpart[4][128][2];       // ctx partial sums (4-way s2 split)
    __shared__ u16 htmp[32][4];
    {
        int r = tid >> 5, kc = tid & 31;
        int gate = r >> 2, jl = r & 3;
        int grow = gate * H + j0 + jl;
        for (int i = 0; i < 12; ++i) {
            int c = kc + 32 * i;
            int k = c * 8;
            v8s wf = load8(wfuse + (size_t)grow * 3072 + k);
            if (k < 1024) {
                v8s wh = load8(dwhh + (size_t)grow * 1024 + k);
                #pragma unroll
                for (int e = 0; e < 8; ++e)
                    wf[e] = (short)f2bf(bf2f((u16)wf[e]) + bf2f((u16)wh[e]));
            }
            *reinterpret_cast<v8s*>(wlds + r * 3072 + ((c ^ (r & 7)) * 8)) = wf;
        }
    }
    const int pb = tid >> 2, pj = tid & 3;
    float creg = 0.f;
    float bsum[4];
    if (tid < 128) {
        creg = decc[(size_t)pb * H + j0 + pj];
        #pragma unroll
        for (int gt = 0; gt < 4; ++gt)
            bsum[gt] = bih[gt * H + j0 + pj] + bhh[gt * H + j0 + pj];
    }
    __syncthreads();
    const int wv = tid >> 6, lane = tid & 63, l15 = lane & 15, lg = lane >> 4;
    const int ab = bid >> 3, ach = bid & 7;     // attention assignment
    for (int t = 0; t < T; ++t) {
        const u16* hp = hc + (size_t)t * (B * 3072);
        u16* hn = hc + (size_t)(t + 1) * (B * 3072);
        // ---- P1: gates = hc[t] @ Wdec^T + xg
        float xv[4];
        if (tid < 128) {
            const float* xr = xgD + (size_t)(t * 32 + pb) * 4096 + j0 + pj;
            #pragma unroll
            for (int gt = 0; gt < 4; ++gt) xv[gt] = xr[gt * H];
        }
        const u16* a0 = hp + (size_t)l15 * 3072 + wv * 384 + 8 * lg;
        const u16* a1 = a0 + (size_t)16 * 3072;
        v4f acc0 = {0.f, 0.f, 0.f, 0.f}, acc1 = {0.f, 0.f, 0.f, 0.f};
        #pragma unroll
        for (int kb = 0; kb < 12; ++kb) {
            int c = wv * 48 + kb * 4 + lg;
            v8s bf = load8(wlds + l15 * 3072 + ((c ^ (l15 & 7)) * 8));
            v8s af0 = load8(a0 + kb * 32);
            v8s af1 = load8(a1 + kb * 32);
            acc0 = MFMA(af0, bf, acc0);
            acc1 = MFMA(af1, bf, acc1);
        }
        #pragma unroll
        for (int r = 0; r < 4; ++r) {
            glds[wv][lg * 4 + r][l15] = acc0[r];
            glds[wv][16 + lg * 4 + r][l15] = acc1[r];
        }
        __syncthreads();
        if (tid < 128) {
            float gv[4];
            #pragma unroll
            for (int gt = 0; gt < 4; ++gt) {
                float v = 0.f;
                #pragma unroll
                for (int w = 0; w < 8; ++w) v += glds[w][pb][gt * 4 + pj];
                gv[gt] = v + xv[gt] + bsum[gt];
            }
            float si = 1.f / (1.f + expf(-gv[0]));
            float sf = 1.f / (1.f + expf(-gv[1]));
            float tg = tanhf(gv[2]);
            float so = 1.f / (1.f + expf(-gv[3]));
            creg = sf * creg + si * tg;
            htmp[pb][pj] = f2bf(so * tanhf(creg));
        }
        __syncthreads();
        if (tid < 64) {
            int rb = tid >> 1, c2 = (tid & 1) * 2;
            unsigned val = (unsigned)htmp[rb][c2] | ((unsigned)htmp[rb][c2 + 1] << 16);
            cstore((unsigned*)(hn + (size_t)rb * 3072 + j0 + c2), val);
        }
        gbar2(bar, bid, 256, 2 * t + 1);
        // ---- P2: attention, spread over 256 blocks (b = bid>>3, ch = bid&7)
        {
            const u16* hb = hn + (size_t)ab * 3072;
            for (int i = tid; i < 1024; i += 512)
                hl[((i >> 7) * 132) + (i & 127)] = bf2f(hb[i]);
            __syncthreads();
            {
                int si2 = tid >> 3, pt = tid & 7;
                const u16* ap = encab + ((size_t)(ab * 64 + si2)) * 1024 + pt * 128;
                const float* hq = hl + pt * 132;
                float ps = 0.f;
                #pragma unroll
                for (int x = 0; x < 16; ++x) {
                    v8s v = load8(ap + x * 8);
                    #pragma unroll
                    for (int e = 0; e < 8; ++e) ps += bf2f((u16)v[e]) * hq[x * 8 + e];
                }
                ps += __shfl_xor(ps, 1); ps += __shfl_xor(ps, 2); ps += __shfl_xor(ps, 4);
                if (pt == 0) sc[si2] = ps;
            }
            __syncthreads();
            if (tid < 64) {
                float v = sc[tid];
                float m = v;
                #pragma unroll
                for (int o = 32; o; o >>= 1) m = fmaxf(m, __shfl_xor(m, o));
                float e = expf(v - m), sum = e;
                #pragma unroll
                for (int o = 32; o; o >>= 1) sum += __shfl_xor(sum, o);
                aw[tid] = e / sum;
            }
            __syncthreads();
            {   // ctx: all 512 threads, 4-way split of s2 range
                int q = tid >> 7, dp = tid & 127;
                int d = ach * 256 + dp * 2;
                const u16* ep = ench + (size_t)ab * S * 2048 + (size_t)(q * 16) * 2048 + d;
                float c0 = 0.f, c1 = 0.f;
                #pragma unroll 8
                for (int s2 = 0; s2 < 16; ++s2) {
                    unsigned uv = *reinterpret_cast<const unsigned*>(ep);
                    float w = aw[q * 16 + s2];
                    c0 += w * bf2f((u16)(uv & 0xFFFF));
                    c1 += w * bf2f((u16)(uv >> 16));
                    ep += 2048;
                }
                cpart[q][dp][0] = c0;
                cpart[q][dp][1] = c1;
            }
            __syncthreads();
            if (tid < 128) {
                float c0 = cpart[0][tid][0] + cpart[1][tid][0]
                         + cpart[2][tid][0] + cpart[3][tid][0];
                float c1 = cpart[0][tid][1] + cpart[1][tid][1]
                         + cpart[2][tid][1] + cpart[3][tid][1];
                unsigned ov = ((unsigned)f2bf(c1) << 16) | f2bf(c0);
                cstore((unsigned*)(hn + (size_t)ab * 3072 + 1024 + ach * 256 + tid * 2), ov);
            }
        }
        if (t < T - 1) gbar2(bar, bid, 256, 2 * t + 2);
    }
}

// ---------------- tiled projection GEMM + fused softmax partials ------------
__global__ __launch_bounds__(512) void k_proj(const u16* __restrict__ A,
                                              const u16* __restrict__ W,
                                              const int* __restrict__ tgt,
                                              float* __restrict__ pmax,
                                              float* __restrict__ psum,
                                              float* __restrict__ pgold) {
    __shared__ __align__(16) u16 As[256 * 64];
    __shared__ __align__(16) u16 Bs[128 * 64];
    __shared__ float red[256][2][3];
    const int tid = threadIdx.x;
    const int lane = tid & 63, wv = tid >> 6;
    const int l15 = lane & 15, lg = lane >> 4;
    const int wr = wv >> 1, wc = wv & 1;
    int orig = blockIdx.x;
    int xcd = orig & 7, loc = orig >> 3;
    int wgid = (xcd < 4 ? xcd * 188 : 752 + (xcd - 4) * 187) + loc;
    int nt = wgid / 6, mt = wgid % 6;
    const int m0 = mt * 256, n0 = nt * 128;
    const int srow = lane >> 3, sc_ = lane & 7;

    v4f acc[4][4];
    #pragma unroll
    for (int i = 0; i < 4; ++i)
        #pragma unroll
        for (int j = 0; j < 4; ++j) acc[i][j] = v4f{0.f, 0.f, 0.f, 0.f};

    for (int kt = 0; kt < 16; ++kt) {
        const int kb = kt * 64;
        #pragma unroll
        for (int i = 0; i < 4; ++i) {
            int chunk = wv * 4 + i;
            int row = chunk * 8 + srow;
            int csw = (sc_ ^ (row & 7)) << 3;
            gload_lds16(A + (size_t)(m0 + row) * 1024 + kb + csw, As + chunk * 512);
        }
        #pragma unroll
        for (int i = 0; i < 2; ++i) {
            int chunk = wv * 2 + i;
            int row = chunk * 8 + srow;
            int csw = (sc_ ^ (row & 7)) << 3;
            gload_lds16(W + (size_t)(n0 + row) * 1024 + kb + csw, Bs + chunk * 512);
        }
        __syncthreads();
        #pragma unroll
        for (int kk = 0; kk < 2; ++kk) {
            int sw = (((kk << 2) | lg) ^ (l15 & 7)) << 3;
            v8s af[4], bfv[4];
            #pragma unroll
            for (int mi = 0; mi < 4; ++mi)
                af[mi] = load8(As + (wr * 64 + mi * 16 + l15) * 64 + sw);
            #pragma unroll
            for (int ni = 0; ni < 4; ++ni)
                bfv[ni] = load8(Bs + (wc * 64 + ni * 16 + l15) * 64 + sw);
            #pragma unroll
            for (int mi = 0; mi < 4; ++mi)
                #pragma unroll
                for (int ni = 0; ni < 4; ++ni)
                    acc[mi][ni] = MFMA(af[mi], bfv[ni], acc[mi][ni]);
        }
        __syncthreads();
    }
    #pragma unroll
    for (int mi = 0; mi < 4; ++mi) {
        #pragma unroll
        for (int rr = 0; rr < 4; ++rr) {
            int lrow = wr * 64 + mi * 16 + lg * 4 + rr;
            int grow = m0 + lrow;
            float vmax = -1e30f;
            #pragma unroll
            for (int ni = 0; ni < 4; ++ni) vmax = fmaxf(vmax, acc[mi][ni][rr]);
            #pragma unroll
            for (int x = 1; x < 16; x <<= 1) vmax = fmaxf(vmax, __shfl_xor(vmax, x));
            float se = 0.f;
            #pragma unroll
            for (int ni = 0; ni < 4; ++ni) se += expf(acc[mi][ni][rr] - vmax);
            #pragma unroll
            for (int x = 1; x < 16; x <<= 1) se += __shfl_xor(se, x);
            int t = grow >> 5, b = grow & 31;
            int g = (grow < MROWS) ? tgt[b * T + t + 1] : -1;
            float gv = 0.f;
            #pragma unroll
            for (int ni = 0; ni < 4; ++ni) {
                int col = n0 + wc * 64 + ni * 16 + l15;
                if (col == g) gv = acc[mi][ni][rr];
            }
            #pragma unroll
            for (int x = 1; x < 16; x <<= 1) gv += __shfl_xor(gv, x);
            if (l15 == 0) {
                red[lrow][wc][0] = vmax;
                red[lrow][wc][1] = se;
                red[lrow][wc][2] = gv;
            }
        }
    }
    __syncthreads();
    if (tid < 256) {
        int grow = m0 + tid;
        if (grow < MROWS) {
            float ma = red[tid][0][0], mb = red[tid][1][0];
            float M = fmaxf(ma, mb);
            float Sv = red[tid][0][1] * expf(ma - M) + red[tid][1][1] * expf(mb - M);
            float G = red[tid][0][2] + red[tid][1][2];
            size_t idx = (size_t)grow * NCH + nt;
            pmax[idx] = M; psum[idx] = Sv; pgold[idx] = G;
        }
    }
}

// ---------------- combine chunks -> logP[row] ----------------
__global__ __launch_bounds__(256) void k_lse(const float* __restrict__ pmax,
                                             const float* __restrict__ psum,
                                             const float* __restrict__ pgold,
                                             float* __restrict__ logP) {
    int item = blockIdx.x * 4 + (threadIdx.x >> 6);
    int lane = threadIdx.x & 63;
    if (item >= MROWS) return;
    float m = -1e30f, g = 0.f;
    for (int c = lane; c < NCH; c += 64) {
        size_t idx = (size_t)item * NCH + c;
        m = fmaxf(m, pmax[idx]);
        g += pgold[idx];
    }
    for (int o = 32; o; o >>= 1) m = fmaxf(m, __shfl_xor(m, o));
    float s = 0.f;
    for (int c = lane; c < NCH; c += 64) {
        size_t idx = (size_t)item * NCH + c;
        s += psum[idx] * expf(pmax[idx] - m);
    }
    for (int o = 32; o; o >>= 1) { s += __shfl_xor(s, o); g += __shfl_xor(g, o); }
    if (lane == 0) logP[item] = g - (m + logf(s));
}

__global__ __launch_bounds__(64) void k_final(const float* __restrict__ logP,
                                              float* __restrict__ out) {
    int b = threadIdx.x;
    if (b < 32) {
        float s = 0.f;
        for (int t = 0; t < TP; ++t) s += logP[t * 32 + b];
        out[b] = s;
    }
}

// ================= host =================
extern "C" void kernel_launch(void* const* d_in, const int* in_sizes, int n_in,
                              void* d_out, int out_size, void* d_ws, size_t ws_size,
                              hipStream_t stream) {
    const int*   seq_in  = (const int*)d_in[0];
    const int*   seq_tgt = (const int*)d_in[1];
    const float* src_emb = (const float*)d_in[2];
    const float* tgt_emb = (const float*)d_in[3];
    const float* eWihF = (const float*)d_in[4];
    const float* eWhhF = (const float*)d_in[5];
    const float* eBihF = (const float*)d_in[6];
    const float* eBhhF = (const float*)d_in[7];
    const float* eWihB = (const float*)d_in[8];
    const float* eWhhB = (const float*)d_in[9];
    const float* eBihB = (const float*)d_in[10];
    const float* eBhhB = (const float*)d_in[11];
    const float* dWih  = (const float*)d_in[12];
    const float* dWhh  = (const float*)d_in[13];
    const float* dBih  = (const float*)d_in[14];
    const float* dBhh  = (const float*)d_in[15];
    const float* WinH  = (const float*)d_in[16];
    const float* WinC  = (const float*)d_in[17];
    const float* Watt  = (const float*)d_in[18];
    const float* Wcomb = (const float*)d_in[19];
    const float* Wproj = (const float*)d_in[20];

    char* ws = (char*)d_ws;
    size_t off = 0;
    auto alloc = [&](size_t bytes) -> char* {
        off = (off + 255) & ~(size_t)255;
        char* p = ws + off;
        off += bytes;
        return p;
    };
    const size_t G4 = 4 * (size_t)H;
    const size_t slot = (size_t)B * H;
    // bf16 weights
    u16* wihf = (u16*)alloc(G4 * E * 2);
    u16* whhf = (u16*)alloc(G4 * H * 2);
    u16* wihb = (u16*)alloc(G4 * E * 2);
    u16* whhb = (u16*)alloc(G4 * H * 2);
    u16* dwih = (u16*)alloc(G4 * (E + H) * 2);
    u16* dwhh = (u16*)alloc(G4 * H * 2);
    u16* winh = (u16*)alloc((size_t)H * 2 * H * 2);
    u16* winc = (u16*)alloc((size_t)H * 2 * H * 2);
    u16* watt = (u16*)alloc((size_t)H * 2 * H * 2);
    u16* wcmb = (u16*)alloc((size_t)H * 3 * H * 2);
    u16* wprj = (u16*)alloc((size_t)V * H * 2);
    u16* wcmbT = (u16*)alloc((size_t)3 * H * H * 2);
    u16* wfuse = (u16*)alloc((size_t)G4 * 3 * H * 2);
    // bf16 activations
    u16* xsrc  = (u16*)alloc((size_t)S * B * E * 2);
    u16* xtgt  = (u16*)alloc((size_t)T * B * E * 2);
    u16* hsf   = (u16*)alloc((size_t)(S + 1) * slot * 2);
    u16* hsb   = (u16*)alloc((size_t)(S + 1) * slot * 2);
    u16* ench  = (u16*)alloc((size_t)B * S * 2 * H * 2);
    u16* encab = (u16*)alloc((size_t)B * S * H * 2);
    u16* hc    = (u16*)alloc((size_t)(T + 1) * B * 3072 * 2);
    u16* outsb = (u16*)alloc((size_t)(T * B) * H * 2);
    u16* lcbf  = (u16*)alloc(2 * slot * 2);
    // f32 buffers
    float* xgF  = (float*)alloc((size_t)S * B * G4 * 4);
    float* xgB  = (float*)alloc((size_t)S * B * G4 * 4);
    float* xgD  = (float*)alloc((size_t)T * B * G4 * 4);
    float* cf2  = (float*)alloc(2 * slot * 4);
    float* decc = (float*)alloc(slot * 4);
    float* pmax  = (float*)alloc((size_t)MROWS * NCH * 4);
    float* psum  = (float*)alloc((size_t)MROWS * NCH * 4);
    float* pgold = (float*)alloc((size_t)MROWS * NCH * 4);
    float* logP  = (float*)alloc((size_t)MROWS * 4);
    int* bars = (int*)alloc(3 * 2048 * 4);
    (void)ws_size; (void)in_sizes; (void)n_in; (void)out_size;

    hipMemsetAsync(hsf, 0, slot * 2, stream);
    hipMemsetAsync(hsb, 0, slot * 2, stream);
    hipMemsetAsync(hc, 0, (size_t)B * 3072 * 2, stream);   // hc[0] (ctx part = 0)
    hipMemsetAsync(bars, 0, 3 * 2048 * 4, stream);

    // merged weight conversions (11 segments, one launch)
    {
        CvtD d;
        const float* srcs[11] = {eWihF, eWhhF, eWihB, eWhhB, dWih, dWhh,
                                 WinH, WinC, Watt, Wcomb, Wproj};
        u16* dsts[11] = {wihf, whhf, wihb, whhb, dwih, dwhh,
                         winh, winc, watt, wcmb, wprj};
        size_t ns[11] = {G4 * E, G4 * H, G4 * E, G4 * H, G4 * (E + H), G4 * H,
                         (size_t)H * 2 * H, (size_t)H * 2 * H, (size_t)H * 2 * H,
                         (size_t)H * 3 * H, (size_t)V * H};
        int blk = 0;
        for (int i = 0; i < 11; ++i) {
            d.src[i] = srcs[i];
            d.dst[i] = dsts[i];
            d.n4[i] = (int)(ns[i] / 4);
            d.start[i] = blk;
            blk += (d.n4[i] + 255) / 256;
        }
        d.start[11] = blk;
        k_cvtm<<<dim3(blk), dim3(256), 0, stream>>>(d);
    }

    k_embed<<<dim3((S * B * (E / 4) + 255) / 256), dim3(256), 0, stream>>>(
        seq_in, S, S, src_emb, xsrc);
    k_embed<<<dim3((T * B * (E / 4) + 255) / 256), dim3(256), 0, stream>>>(
        seq_tgt, T, T, tgt_emb, xtgt);

    k_transp<<<dim3(3 * H / 64, H / 64), dim3(256), 0, stream>>>(wcmb, wcmbT, H, 3 * H);

    // prefolded input gates: xg = x @ Wih^T (f32)
    k_tile<<<dim3(32, 16), dim3(256), 0, stream>>>(xsrc, E, wihf, E, xgF, nullptr, 4096, 8);
    k_tile<<<dim3(32, 16), dim3(256), 0, stream>>>(xsrc, E, wihb, E, xgB, nullptr, 4096, 8);
    k_tile<<<dim3(32, 12), dim3(256), 0, stream>>>(xtgt, E, dwih, E + H, xgD, nullptr, 4096, 8);
    k_tile<<<dim3(24, 32), dim3(256), 0, stream>>>(dwih + E, E + H, wcmbT, H,
                                                   nullptr, wfuse, 3 * H, 16);

    // ---------- persistent bidirectional encoder ----------
    k_enc<<<dim3(512), dim3(512), 0, stream>>>(xgF, xgB, whhf, whhb,
                                               eBihF, eBhhF, eBihB, eBhhB,
                                               hsf, hsb, cf2, bars);

    k_ench<<<dim3(B * S * (2 * H / 8) / 256), dim3(256), 0, stream>>>(hsf, hsb, ench);
    k_tile<<<dim3(8, 16), dim3(256), 0, stream>>>(ench, 2 * H, watt, 2 * H,
                                                  nullptr, encab, H, 32);
    {
        int n4 = (int)(2 * slot / 4);
        k_cvt<<<dim3((n4 + 255) / 256), dim3(256), 0, stream>>>(cf2, lcbf, n4);
    }

    // decoder init: dec_h0 directly into hc[0] (bf16, stride 3072); c0; xgD corr
    {
        Seg a1{hsf + (size_t)S * slot, H, winh, 2 * H, H};
        Seg a2{hsb + (size_t)S * slot, H, winh + H, 2 * H, H};
        k_mm<<<dim3(H / 16), dim3(512), 0, stream>>>(a1, a2, nullptr, hc, 3072,
                                                     2 * H / 8, 0);
        Seg c1{lcbf, H, winc, 2 * H, H};
        Seg c2{lcbf + slot, H, winc + H, 2 * H, H};
        k_mm<<<dim3(H / 16), dim3(512), 0, stream>>>(c1, c2, decc, nullptr, H,
                                                     2 * H / 8, 0);
        // xgD[0] -= hc[0] @ Wfuse_h^T   (sub-mode)
        Seg f1{hc, 3072, wfuse, 3 * H, H};
        Seg f0{nullptr, 0, nullptr, 0, 0};
        k_mm<<<dim3(G4 / 16), dim3(512), 0, stream>>>(f1, f0, xgD, nullptr, 4096,
                                                      H / 8, 1);
    }

    // ---------- persistent attention decoder ----------
    k_dec<<<dim3(256), dim3(512), 0, stream>>>(xgD, dwhh, wfuse, dBih, dBhh, decc,
                                               encab, ench, hc, bars + 4096);

    // outs = hc[1..48] @ Wcomb^T (bf16)
    k_tile<<<dim3(8, 12), dim3(256), 0, stream>>>(hc + B * 3072, 3 * H, wcmb, 3 * H,
                                                  nullptr, outsb, H, 48);

    // ---------- vocab projection + log-softmax ----------
    k_proj<<<dim3(1500), dim3(512), 0, stream>>>(outsb, wprj, seq_tgt, pmax, psum, pgold);
    k_lse<<<dim3((MROWS + 3) / 4), dim3(256), 0, stream>>>(pmax, psum, pgold, logP);
    k_final<<<dim3(1), dim3(64), 0, stream>>>(logP, (float*)d_out);
}

// Round 14
// 1370.365 us; speedup vs baseline: 1.6117x; 1.0362x over previous
//
#include <hip/hip_runtime.h>

typedef short v8s __attribute__((ext_vector_type(8)));
typedef float v4f __attribute__((ext_vector_type(4)));
typedef unsigned short u16;

#define DI __device__ __forceinline__
#define MFMA(a, b, c) __builtin_amdgcn_mfma_f32_16x16x32_bf16(a, b, c, 0, 0, 0)

constexpr int B = 32, S = 64, T = 48, E = 512, H = 1024, V = 32000;
constexpr int TP = T - 1;        // 47 prediction steps
constexpr int MROWS = TP * B;    // 1504 valid proj rows
constexpr int NCH = 250;         // 32000 / 128 vocab chunks

DI u16 f2bf(float f) {
    unsigned u = __float_as_uint(f);
    unsigned r = (u + 0x7FFFu + ((u >> 16) & 1u)) >> 16;
    return (u16)r;
}
DI float bf2f(u16 h) { return __uint_as_float(((unsigned)h) << 16); }
DI v8s load8(const u16* p) { return *reinterpret_cast<const v8s*>(p); }

typedef __attribute__((address_space(1))) const unsigned int gu32;
typedef __attribute__((address_space(3))) unsigned int lu32;
DI void gload_lds16(const u16* g, u16* l) {
    __builtin_amdgcn_global_load_lds((gu32*)g, (lu32*)l, 16, 0, 0);
}

// coherence-point u32 store (bypasses private L2; visible to all XCDs)
DI void cstore(unsigned* p, unsigned v) {
    __hip_atomic_store(p, v, __ATOMIC_RELAXED, __HIP_MEMORY_SCOPE_AGENT);
}
DI int cload(const int* p) {
    return __hip_atomic_load(p, __ATOMIC_RELAXED, __HIP_MEMORY_SCOPE_AGENT);
}

// ---------------- root-scan grid barrier (R5/R9 proven) ----------------------
DI void gbar2(int* bar, int bid, int nblk, int v) {
    __syncthreads();
    if (bid == 0) {
        int t = threadIdx.x;
        if (t > 0 && t < nblk) {
            while (cload(bar + 16 + t * 4) < v) __builtin_amdgcn_s_sleep(1);
        }
        __syncthreads();
        if (t == 0)
            __hip_atomic_store(bar, v, __ATOMIC_RELAXED, __HIP_MEMORY_SCOPE_AGENT);
    } else {
        if (threadIdx.x == 0) {
            __hip_atomic_store(bar + 16 + bid * 4, v, __ATOMIC_RELAXED,
                               __HIP_MEMORY_SCOPE_AGENT);
            while (cload(bar) < v) __builtin_amdgcn_s_sleep(2);
        }
        __syncthreads();
    }
}

// ---------------- elementwise conversion f32 -> bf16 ----------------
__global__ __launch_bounds__(256) void k_cvt(const float* __restrict__ s,
                                             u16* __restrict__ d, int n4) {
    int i = blockIdx.x * 256 + threadIdx.x;
    if (i >= n4) return;
    float4 v = reinterpret_cast<const float4*>(s)[i];
    ushort4 o;
    o.x = f2bf(v.x); o.y = f2bf(v.y); o.z = f2bf(v.z); o.w = f2bf(v.w);
    reinterpret_cast<ushort4*>(d)[i] = o;
}

// ---------------- merged multi-segment conversion ----------------
struct CvtD {
    const float* src[11];
    u16* dst[11];
    int n4[11];
    int start[12];
};
__global__ __launch_bounds__(256) void k_cvtm(CvtD d) {
    int blk = blockIdx.x;
    int seg = 0;
    #pragma unroll
    for (int q = 0; q < 11; ++q)
        if (blk >= d.start[q + 1]) seg = q + 1;
    int i = (blk - d.start[seg]) * 256 + threadIdx.x;
    if (i >= d.n4[seg]) return;
    float4 v = reinterpret_cast<const float4*>(d.src[seg])[i];
    ushort4 o;
    o.x = f2bf(v.x); o.y = f2bf(v.y); o.z = f2bf(v.z); o.w = f2bf(v.w);
    reinterpret_cast<ushort4*>(d.dst[seg])[i] = o;
}

// ---------------- embedding gather ----------------
__global__ __launch_bounds__(256) void k_embed(const int* __restrict__ seq, int seqstr,
                                               int nsteps, const float* __restrict__ emb,
                                               u16* __restrict__ out) {
    int i = blockIdx.x * 256 + threadIdx.x;
    int total = nsteps * B * (E / 4);
    if (i >= total) return;
    int q = i & 127;
    int sb = i >> 7;
    int b = sb & 31;
    int s = sb >> 5;
    int tok = seq[b * seqstr + s];
    float4 v = reinterpret_cast<const float4*>(emb + (size_t)tok * E)[q];
    ushort4 o;
    o.x = f2bf(v.x); o.y = f2bf(v.y); o.z = f2bf(v.z); o.w = f2bf(v.w);
    reinterpret_cast<ushort4*>(out + ((size_t)(s * B + b)) * E)[q] = o;
}

// ---------------- build ench[b][s][2H] from hsf/hsb ----------------
__global__ __launch_bounds__(256) void k_ench(const u16* __restrict__ hsf,
                                              const u16* __restrict__ hsb,
                                              u16* __restrict__ ench) {
    int id = blockIdx.x * 256 + threadIdx.x;
    int d8 = id & 255; int s = (id >> 8) & 63; int b = id >> 14;
    int d0 = d8 * 8;
    const u16* src = (d0 < H) ? hsf + (((size_t)(s + 1) * B + b)) * H + d0
                              : hsb + (((size_t)(S - s) * B + b)) * H + (d0 - H);
    *reinterpret_cast<v8s*>(ench + ((size_t)b * S + s) * 2 * H + d0) = load8(src);
}

// ---------------- transpose: out[n][k] = in[k][n], in K x N -----------------
__global__ __launch_bounds__(256) void k_transp(const u16* __restrict__ in,
                                                u16* __restrict__ out, int K, int N) {
    __shared__ u16 t[64][72];
    int nt = blockIdx.x * 64, kt = blockIdx.y * 64;
    int tid = threadIdx.x;
    int r = tid >> 2, cq = (tid & 3) * 16;
    v8s v0 = load8(in + (size_t)(kt + r) * N + nt + cq);
    v8s v1 = load8(in + (size_t)(kt + r) * N + nt + cq + 8);
    #pragma unroll
    for (int e = 0; e < 8; ++e) { t[r][cq + e] = (u16)v0[e]; t[r][cq + 8 + e] = (u16)v1[e]; }
    __syncthreads();
    v8s o0, o1;
    #pragma unroll
    for (int e = 0; e < 8; ++e) { o0[e] = (short)t[cq + e][r]; o1[e] = (short)t[cq + 8 + e][r]; }
    *reinterpret_cast<v8s*>(out + (size_t)(nt + r) * K + kt + cq) = o0;
    *reinterpret_cast<v8s*>(out + (size_t)(nt + r) * K + kt + cq + 8) = o1;
}

// ---------------- generic tiled GEMM: out = A @ W^T (128x128 tile) ----------
__global__ __launch_bounds__(256) void k_tile(const u16* __restrict__ A, int astr,
                                              const u16* __restrict__ W, int wstr,
                                              float* __restrict__ outf,
                                              u16* __restrict__ outb, int ostr,
                                              int ktiles) {
    __shared__ __align__(16) u16 As[128 * 64];
    __shared__ __align__(16) u16 Bs[128 * 64];
    const int tid = threadIdx.x;
    const int lane = tid & 63, wv = tid >> 6;
    const int l15 = lane & 15, lg = lane >> 4;
    const int wr = wv >> 1, wc = wv & 1;
    const int m0 = blockIdx.y * 128, n0 = blockIdx.x * 128;
    const int srow = lane >> 3, sc_ = lane & 7;

    v4f acc[4][4];
    #pragma unroll
    for (int i = 0; i < 4; ++i)
        #pragma unroll
        for (int j = 0; j < 4; ++j) acc[i][j] = v4f{0.f, 0.f, 0.f, 0.f};

    for (int kt = 0; kt < ktiles; ++kt) {
        const int kb = kt * 64;
        #pragma unroll
        for (int i = 0; i < 4; ++i) {
            int chunk = wv * 4 + i;
            int row = chunk * 8 + srow;
            int csw = (sc_ ^ (row & 7)) << 3;
            gload_lds16(A + (size_t)(m0 + row) * astr + kb + csw, As + chunk * 512);
            gload_lds16(W + (size_t)(n0 + row) * wstr + kb + csw, Bs + chunk * 512);
        }
        __syncthreads();
        #pragma unroll
        for (int kk = 0; kk < 2; ++kk) {
            int sw = (((kk << 2) | lg) ^ (l15 & 7)) << 3;
            v8s af[4], bfv[4];
            #pragma unroll
            for (int mi = 0; mi < 4; ++mi)
                af[mi] = load8(As + (wr * 64 + mi * 16 + l15) * 64 + sw);
            #pragma unroll
            for (int ni = 0; ni < 4; ++ni)
                bfv[ni] = load8(Bs + (wc * 64 + ni * 16 + l15) * 64 + sw);
            #pragma unroll
            for (int mi = 0; mi < 4; ++mi)
                #pragma unroll
                for (int ni = 0; ni < 4; ++ni)
                    acc[mi][ni] = MFMA(af[mi], bfv[ni], acc[mi][ni]);
        }
        __syncthreads();
    }
    #pragma unroll
    for (int mi = 0; mi < 4; ++mi)
        #pragma unroll
        for (int rr = 0; rr < 4; ++rr) {
            int row = m0 + wr * 64 + mi * 16 + lg * 4 + rr;
            #pragma unroll
            for (int ni = 0; ni < 4; ++ni) {
                int col = n0 + wc * 64 + ni * 16 + l15;
                if (outf) outf[(size_t)row * ostr + col] = acc[mi][ni][rr];
                else      outb[(size_t)row * ostr + col] = f2bf(acc[mi][ni][rr]);
            }
        }
}

// ---------------- merged 4-segment tiled GEMM (prep GEMMs, one launch) ------
struct T4 {
    const u16* A[4]; int astr[4];
    const u16* W[4]; int wstr[4];
    float* outf[4]; u16* outb[4]; int ostr[4];
    int kt[4]; int nx[4]; int start[5];
};
__global__ __launch_bounds__(256) void k_tile4(T4 p) {
    __shared__ __align__(16) u16 As[128 * 64];
    __shared__ __align__(16) u16 Bs[128 * 64];
    int blk = blockIdx.x;
    int seg = 0;
    #pragma unroll
    for (int q = 0; q < 3; ++q)
        if (blk >= p.start[q + 1]) seg = q + 1;
    int lid = blk - p.start[seg];
    const int n0 = (lid % p.nx[seg]) * 128;
    const int m0 = (lid / p.nx[seg]) * 128;
    const u16* A = p.A[seg];
    const u16* W = p.W[seg];
    const int astr = p.astr[seg], wstr = p.wstr[seg], ostr = p.ostr[seg];
    float* outf = p.outf[seg];
    u16* outb = p.outb[seg];
    const int ktiles = p.kt[seg];
    const int tid = threadIdx.x;
    const int lane = tid & 63, wv = tid >> 6;
    const int l15 = lane & 15, lg = lane >> 4;
    const int wr = wv >> 1, wc = wv & 1;
    const int srow = lane >> 3, sc_ = lane & 7;

    v4f acc[4][4];
    #pragma unroll
    for (int i = 0; i < 4; ++i)
        #pragma unroll
        for (int j = 0; j < 4; ++j) acc[i][j] = v4f{0.f, 0.f, 0.f, 0.f};

    for (int kt = 0; kt < ktiles; ++kt) {
        const int kb = kt * 64;
        #pragma unroll
        for (int i = 0; i < 4; ++i) {
            int chunk = wv * 4 + i;
            int row = chunk * 8 + srow;
            int csw = (sc_ ^ (row & 7)) << 3;
            gload_lds16(A + (size_t)(m0 + row) * astr + kb + csw, As + chunk * 512);
            gload_lds16(W + (size_t)(n0 + row) * wstr + kb + csw, Bs + chunk * 512);
        }
        __syncthreads();
        #pragma unroll
        for (int kk = 0; kk < 2; ++kk) {
            int sw = (((kk << 2) | lg) ^ (l15 & 7)) << 3;
            v8s af[4], bfv[4];
            #pragma unroll
            for (int mi = 0; mi < 4; ++mi)
                af[mi] = load8(As + (wr * 64 + mi * 16 + l15) * 64 + sw);
            #pragma unroll
            for (int ni = 0; ni < 4; ++ni)
                bfv[ni] = load8(Bs + (wc * 64 + ni * 16 + l15) * 64 + sw);
            #pragma unroll
            for (int mi = 0; mi < 4; ++mi)
                #pragma unroll
                for (int ni = 0; ni < 4; ++ni)
                    acc[mi][ni] = MFMA(af[mi], bfv[ni], acc[mi][ni]);
        }
        __syncthreads();
    }
    #pragma unroll
    for (int mi = 0; mi < 4; ++mi)
        #pragma unroll
        for (int rr = 0; rr < 4; ++rr) {
            int row = m0 + wr * 64 + mi * 16 + lg * 4 + rr;
            #pragma unroll
            for (int ni = 0; ni < 4; ++ni) {
                int col = n0 + wc * 64 + ni * 16 + l15;
                if (outf) outf[(size_t)row * ostr + col] = acc[mi][ni][rr];
                else      outb[(size_t)row * ostr + col] = f2bf(acc[mi][ni][rr]);
            }
        }
}

// ---------------- split-K small GEMM (M=32), sub-mode -----------------------
struct Seg { const u16* a; int astr; const u16* w; int wstr; int k; };

__global__ __launch_bounds__(512) void k_mm(Seg s1, Seg s2, float* __restrict__ outf,
                                            u16* __restrict__ outb, int ostr, int ks,
                                            int sub) {
    const int tid = threadIdx.x;
    const int wv = tid >> 6, lane = tid & 63;
    const int l15 = lane & 15, lg = lane >> 4;
    const int wrow = blockIdx.x * 16 + l15;
    const int k0 = wv * ks, k1 = k0 + ks;
    v4f acc0 = {0.f, 0.f, 0.f, 0.f}, acc1 = {0.f, 0.f, 0.f, 0.f};
    int base = 0;
    auto doseg = [&](const Seg& sg) {
        if (sg.k == 0) return;
        int s0 = k0 > base ? k0 : base;
        int send = base + sg.k;
        int s1e = k1 < send ? k1 : send;
        const u16* wp = sg.w + (size_t)wrow * sg.wstr + 8 * lg;
        const u16* a0p = sg.a + (size_t)l15 * sg.astr + 8 * lg;
        const u16* a1p = sg.a + (size_t)(16 + l15) * sg.astr + 8 * lg;
        #pragma unroll 2
        for (int k = s0; k < s1e; k += 32) {
            int kl = k - base;
            v8s bf = load8(wp + kl);
            v8s af0 = load8(a0p + kl);
            v8s af1 = load8(a1p + kl);
            acc0 = MFMA(af0, bf, acc0);
            acc1 = MFMA(af1, bf, acc1);
        }
        base += sg.k;
    };
    doseg(s1); doseg(s2);

    __shared__ float g[8][32][16];
    #pragma unroll
    for (int r = 0; r < 4; ++r) {
        g[wv][lg * 4 + r][l15] = acc0[r];
        g[wv][16 + lg * 4 + r][l15] = acc1[r];
    }
    __syncthreads();
    {
        int b = tid >> 4, cl = tid & 15;
        float v = 0.f;
        #pragma unroll
        for (int w = 0; w < 8; ++w) v += g[w][b][cl];
        int col = blockIdx.x * 16 + cl;
        size_t idx = (size_t)b * ostr + col;
        if (outb)      outb[idx] = f2bf(v);
        else if (sub)  outf[idx] -= v;
        else           outf[idx] = v;
    }
}

// ---------------- persistent bidirectional encoder ---------------------------
// 128 blocks/dir x 512 thr; 8 output cols/block; Whh slice (64KB) in LDS.
__global__ __launch_bounds__(512) void k_enc(
    const float* __restrict__ xgF, const float* __restrict__ xgB,
    const u16* __restrict__ whhf, const u16* __restrict__ whhb,
    const float* __restrict__ bihF, const float* __restrict__ bhhF,
    const float* __restrict__ bihB, const float* __restrict__ bhhB,
    u16* __restrict__ hsf, u16* __restrict__ hsb,
    float* __restrict__ cfinal, int* __restrict__ bars) {
    const int blk = blockIdx.x;
    const int dir = blk >> 7, bid = blk & 127;
    const int tid = threadIdx.x;
    const u16* whh = dir ? whhb : whhf;
    const float* xg = dir ? xgB : xgF;
    const float* bih = dir ? bihB : bihF;
    const float* bhh = dir ? bhhB : bhhF;
    u16* hs = dir ? hsb : hsf;
    int* bar = bars + dir * 2048;
    const int j0 = bid * 8;
    __shared__ u16 wlds[32 * 1024];          // 64 KB: 32 weight rows (4 gates x 8)
    __shared__ float glds[8][32][34];        // ~34 KB
    __shared__ u16 htmp[32][8];
    {   // weight load: 32 rows x K=1024, swizzled
        int r = tid >> 4, kc = tid & 15;
        int gate = r >> 3, jl = r & 7;
        const u16* src = whh + (size_t)(gate * H + j0 + jl) * H;
        #pragma unroll
        for (int i = 0; i < 8; ++i) {
            int c = kc + 16 * i;
            v8s v = load8(src + c * 8);
            *reinterpret_cast<v8s*>(wlds + r * 1024 + ((c ^ (r & 7)) * 8)) = v;
        }
    }
    float creg = 0.f;
    const int pb = tid >> 3, pj = tid & 7;
    float bsum[4];
    if (tid < 256) {
        #pragma unroll
        for (int gt = 0; gt < 4; ++gt)
            bsum[gt] = bih[gt * H + j0 + pj] + bhh[gt * H + j0 + pj];
    }
    __syncthreads();
    const int wv = tid >> 6, lane = tid & 63, l15 = lane & 15, lg = lane >> 4;
    for (int s = 0; s < S; ++s) {
        float xv[4];
        if (tid < 256) {
            int xrow = ((dir ? (S - 1 - s) : s) * 32 + pb) * 4096;
            const float* xr = xg + xrow + j0 + pj;
            #pragma unroll
            for (int gt = 0; gt < 4; ++gt) xv[gt] = xr[gt * H];
        }
        const u16* hp = hs + (size_t)s * (B * H);
        const u16* a0 = hp + (size_t)l15 * H + wv * 128 + 8 * lg;
        const u16* a1 = a0 + (size_t)16 * H;
        v4f acc00 = {0,0,0,0}, acc01 = {0,0,0,0}, acc10 = {0,0,0,0}, acc11 = {0,0,0,0};
        #pragma unroll
        for (int kb = 0; kb < 4; ++kb) {
            int c = wv * 16 + kb * 4 + lg;
            int w0 = l15;          // weight rows 0..15
            int w1 = 16 + l15;     // weight rows 16..31
            v8s bf0 = load8(wlds + w0 * 1024 + ((c ^ (w0 & 7)) * 8));
            v8s bf1 = load8(wlds + w1 * 1024 + ((c ^ (w1 & 7)) * 8));
            v8s af0 = load8(a0 + kb * 32);
            v8s af1 = load8(a1 + kb * 32);
            acc00 = MFMA(af0, bf0, acc00);
            acc10 = MFMA(af0, bf1, acc10);
            acc01 = MFMA(af1, bf0, acc01);
            acc11 = MFMA(af1, bf1, acc11);
        }
        #pragma unroll
        for (int r = 0; r < 4; ++r) {
            glds[wv][lg * 4 + r][l15] = acc00[r];
            glds[wv][lg * 4 + r][16 + l15] = acc10[r];
            glds[wv][16 + lg * 4 + r][l15] = acc01[r];
            glds[wv][16 + lg * 4 + r][16 + l15] = acc11[r];
        }
        __syncthreads();
        if (tid < 256) {
            float gv[4];
            #pragma unroll
            for (int gt = 0; gt < 4; ++gt) {
                float v = 0.f;
                #pragma unroll
                for (int w = 0; w < 8; ++w) v += glds[w][pb][gt * 8 + pj];
                gv[gt] = v + xv[gt] + bsum[gt];
            }
            float si = 1.f / (1.f + expf(-gv[0]));
            float sf = 1.f / (1.f + expf(-gv[1]));
            float tg = tanhf(gv[2]);
            float so = 1.f / (1.f + expf(-gv[3]));
            creg = sf * creg + si * tg;
            htmp[pb][pj] = f2bf(so * tanhf(creg));
        }
        __syncthreads();
        if (tid < 128) {
            int rb = tid >> 2, c2 = (tid & 3) * 2;
            unsigned val = (unsigned)htmp[rb][c2] | ((unsigned)htmp[rb][c2 + 1] << 16);
            cstore((unsigned*)(hs + (size_t)(s + 1) * (B * H) + (size_t)rb * H + j0 + c2), val);
        }
        if (s < S - 1) gbar2(bar, bid, 128, s + 1);
    }
    if (tid < 256) cfinal[(size_t)dir * B * H + (size_t)pb * H + j0 + pj] = creg;
}

// ---------------- persistent attention decoder (R13 proven) ------------------
__global__ __launch_bounds__(512) void k_dec(
    const float* __restrict__ xgD, const u16* __restrict__ dwhh,
    const u16* __restrict__ wfuse, const float* __restrict__ bih,
    const float* __restrict__ bhh, const float* __restrict__ decc,
    const u16* __restrict__ encab, const u16* __restrict__ ench,
    u16* __restrict__ hc, int* __restrict__ bar) {
    const int bid = blockIdx.x, tid = threadIdx.x;
    const int j0 = bid * 4;
    __shared__ u16 wlds[16 * 3072];
    __shared__ float glds[8][32][16];
    __shared__ float hl[1056];               // 132-stride padded
    __shared__ float sc[64], aw[64];
    __shared__ float cpart[4][128][2];       // ctx partial sums (4-way s2 split)
    __shared__ u16 htmp[32][4];
    {
        int r = tid >> 5, kc = tid & 31;
        int gate = r >> 2, jl = r & 3;
        int grow = gate * H + j0 + jl;
        for (int i = 0; i < 12; ++i) {
            int c = kc + 32 * i;
            int k = c * 8;
            v8s wf = load8(wfuse + (size_t)grow * 3072 + k);
            if (k < 1024) {
                v8s wh = load8(dwhh + (size_t)grow * 1024 + k);
                #pragma unroll
                for (int e = 0; e < 8; ++e)
                    wf[e] = (short)f2bf(bf2f((u16)wf[e]) + bf2f((u16)wh[e]));
            }
            *reinterpret_cast<v8s*>(wlds + r * 3072 + ((c ^ (r & 7)) * 8)) = wf;
        }
    }
    const int pb = tid >> 2, pj = tid & 3;
    float creg = 0.f;
    float bsum[4];
    if (tid < 128) {
        creg = decc[(size_t)pb * H + j0 + pj];
        #pragma unroll
        for (int gt = 0; gt < 4; ++gt)
            bsum[gt] = bih[gt * H + j0 + pj] + bhh[gt * H + j0 + pj];
    }
    __syncthreads();
    const int wv = tid >> 6, lane = tid & 63, l15 = lane & 15, lg = lane >> 4;
    const int ab = bid >> 3, ach = bid & 7;     // attention assignment
    for (int t = 0; t < T; ++t) {
        const u16* hp = hc + (size_t)t * (B * 3072);
        u16* hn = hc + (size_t)(t + 1) * (B * 3072);
        // ---- P1: gates = hc[t] @ Wdec^T + xg
        float xv[4];
        if (tid < 128) {
            const float* xr = xgD + (size_t)(t * 32 + pb) * 4096 + j0 + pj;
            #pragma unroll
            for (int gt = 0; gt < 4; ++gt) xv[gt] = xr[gt * H];
        }
        const u16* a0 = hp + (size_t)l15 * 3072 + wv * 384 + 8 * lg;
        const u16* a1 = a0 + (size_t)16 * 3072;
        v4f acc0 = {0.f, 0.f, 0.f, 0.f}, acc1 = {0.f, 0.f, 0.f, 0.f};
        #pragma unroll
        for (int kb = 0; kb < 12; ++kb) {
            int c = wv * 48 + kb * 4 + lg;
            v8s bf = load8(wlds + l15 * 3072 + ((c ^ (l15 & 7)) * 8));
            v8s af0 = load8(a0 + kb * 32);
            v8s af1 = load8(a1 + kb * 32);
            acc0 = MFMA(af0, bf, acc0);
            acc1 = MFMA(af1, bf, acc1);
        }
        #pragma unroll
        for (int r = 0; r < 4; ++r) {
            glds[wv][lg * 4 + r][l15] = acc0[r];
            glds[wv][16 + lg * 4 + r][l15] = acc1[r];
        }
        __syncthreads();
        if (tid < 128) {
            float gv[4];
            #pragma unroll
            for (int gt = 0; gt < 4; ++gt) {
                float v = 0.f;
                #pragma unroll
                for (int w = 0; w < 8; ++w) v += glds[w][pb][gt * 4 + pj];
                gv[gt] = v + xv[gt] + bsum[gt];
            }
            float si = 1.f / (1.f + expf(-gv[0]));
            float sf = 1.f / (1.f + expf(-gv[1]));
            float tg = tanhf(gv[2]);
            float so = 1.f / (1.f + expf(-gv[3]));
            creg = sf * creg + si * tg;
            htmp[pb][pj] = f2bf(so * tanhf(creg));
        }
        __syncthreads();
        if (tid < 64) {
            int rb = tid >> 1, c2 = (tid & 1) * 2;
            unsigned val = (unsigned)htmp[rb][c2] | ((unsigned)htmp[rb][c2 + 1] << 16);
            cstore((unsigned*)(hn + (size_t)rb * 3072 + j0 + c2), val);
        }
        gbar2(bar, bid, 256, 2 * t + 1);
        // ---- P2: attention, spread over 256 blocks (b = bid>>3, ch = bid&7)
        {
            const u16* hb = hn + (size_t)ab * 3072;
            for (int i = tid; i < 1024; i += 512)
                hl[((i >> 7) * 132) + (i & 127)] = bf2f(hb[i]);
            __syncthreads();
            {
                int si2 = tid >> 3, pt = tid & 7;
                const u16* ap = encab + ((size_t)(ab * 64 + si2)) * 1024 + pt * 128;
                const float* hq = hl + pt * 132;
                float ps = 0.f;
                #pragma unroll
                for (int x = 0; x < 16; ++x) {
                    v8s v = load8(ap + x * 8);
                    #pragma unroll
                    for (int e = 0; e < 8; ++e) ps += bf2f((u16)v[e]) * hq[x * 8 + e];
                }
                ps += __shfl_xor(ps, 1); ps += __shfl_xor(ps, 2); ps += __shfl_xor(ps, 4);
                if (pt == 0) sc[si2] = ps;
            }
            __syncthreads();
            if (tid < 64) {
                float v = sc[tid];
                float m = v;
                #pragma unroll
                for (int o = 32; o; o >>= 1) m = fmaxf(m, __shfl_xor(m, o));
                float e = expf(v - m), sum = e;
                #pragma unroll
                for (int o = 32; o; o >>= 1) sum += __shfl_xor(sum, o);
                aw[tid] = e / sum;
            }
            __syncthreads();
            {   // ctx: all 512 threads, 4-way split of s2 range
                int q = tid >> 7, dp = tid & 127;
                int d = ach * 256 + dp * 2;
                const u16* ep = ench + (size_t)ab * S * 2048 + (size_t)(q * 16) * 2048 + d;
                float c0 = 0.f, c1 = 0.f;
                #pragma unroll 8
                for (int s2 = 0; s2 < 16; ++s2) {
                    unsigned uv = *reinterpret_cast<const unsigned*>(ep);
                    float w = aw[q * 16 + s2];
                    c0 += w * bf2f((u16)(uv & 0xFFFF));
                    c1 += w * bf2f((u16)(uv >> 16));
                    ep += 2048;
                }
                cpart[q][dp][0] = c0;
                cpart[q][dp][1] = c1;
            }
            __syncthreads();
            if (tid < 128) {
                float c0 = cpart[0][tid][0] + cpart[1][tid][0]
                         + cpart[2][tid][0] + cpart[3][tid][0];
                float c1 = cpart[0][tid][1] + cpart[1][tid][1]
                         + cpart[2][tid][1] + cpart[3][tid][1];
                unsigned ov = ((unsigned)f2bf(c1) << 16) | f2bf(c0);
                cstore((unsigned*)(hn + (size_t)ab * 3072 + 1024 + ach * 256 + tid * 2), ov);
            }
        }
        if (t < T - 1) gbar2(bar, bid, 256, 2 * t + 2);
    }
}

// ---------------- tiled projection GEMM + fused softmax partials ------------
__global__ __launch_bounds__(512) void k_proj(const u16* __restrict__ A,
                                              const u16* __restrict__ W,
                                              const int* __restrict__ tgt,
                                              float* __restrict__ pmax,
                                              float* __restrict__ psum,
                                              float* __restrict__ pgold) {
    __shared__ __align__(16) u16 As[256 * 64];
    __shared__ __align__(16) u16 Bs[128 * 64];
    __shared__ float red[256][2][3];
    const int tid = threadIdx.x;
    const int lane = tid & 63, wv = tid >> 6;
    const int l15 = lane & 15, lg = lane >> 4;
    const int wr = wv >> 1, wc = wv & 1;
    int orig = blockIdx.x;
    int xcd = orig & 7, loc = orig >> 3;
    int wgid = (xcd < 4 ? xcd * 188 : 752 + (xcd - 4) * 187) + loc;
    int nt = wgid / 6, mt = wgid % 6;
    const int m0 = mt * 256, n0 = nt * 128;
    const int srow = lane >> 3, sc_ = lane & 7;

    v4f acc[4][4];
    #pragma unroll
    for (int i = 0; i < 4; ++i)
        #pragma unroll
        for (int j = 0; j < 4; ++j) acc[i][j] = v4f{0.f, 0.f, 0.f, 0.f};

    for (int kt = 0; kt < 16; ++kt) {
        const int kb = kt * 64;
        #pragma unroll
        for (int i = 0; i < 4; ++i) {
            int chunk = wv * 4 + i;
            int row = chunk * 8 + srow;
            int csw = (sc_ ^ (row & 7)) << 3;
            gload_lds16(A + (size_t)(m0 + row) * 1024 + kb + csw, As + chunk * 512);
        }
        #pragma unroll
        for (int i = 0; i < 2; ++i) {
            int chunk = wv * 2 + i;
            int row = chunk * 8 + srow;
            int csw = (sc_ ^ (row & 7)) << 3;
            gload_lds16(W + (size_t)(n0 + row) * 1024 + kb + csw, Bs + chunk * 512);
        }
        __syncthreads();
        #pragma unroll
        for (int kk = 0; kk < 2; ++kk) {
            int sw = (((kk << 2) | lg) ^ (l15 & 7)) << 3;
            v8s af[4], bfv[4];
            #pragma unroll
            for (int mi = 0; mi < 4; ++mi)
                af[mi] = load8(As + (wr * 64 + mi * 16 + l15) * 64 + sw);
            #pragma unroll
            for (int ni = 0; ni < 4; ++ni)
                bfv[ni] = load8(Bs + (wc * 64 + ni * 16 + l15) * 64 + sw);
            #pragma unroll
            for (int mi = 0; mi < 4; ++mi)
                #pragma unroll
                for (int ni = 0; ni < 4; ++ni)
                    acc[mi][ni] = MFMA(af[mi], bfv[ni], acc[mi][ni]);
        }
        __syncthreads();
    }
    #pragma unroll
    for (int mi = 0; mi < 4; ++mi) {
        #pragma unroll
        for (int rr = 0; rr < 4; ++rr) {
            int lrow = wr * 64 + mi * 16 + lg * 4 + rr;
            int grow = m0 + lrow;
            float vmax = -1e30f;
            #pragma unroll
            for (int ni = 0; ni < 4; ++ni) vmax = fmaxf(vmax, acc[mi][ni][rr]);
            #pragma unroll
            for (int x = 1; x < 16; x <<= 1) vmax = fmaxf(vmax, __shfl_xor(vmax, x));
            float se = 0.f;
            #pragma unroll
            for (int ni = 0; ni < 4; ++ni) se += expf(acc[mi][ni][rr] - vmax);
            #pragma unroll
            for (int x = 1; x < 16; x <<= 1) se += __shfl_xor(se, x);
            int t = grow >> 5, b = grow & 31;
            int g = (grow < MROWS) ? tgt[b * T + t + 1] : -1;
            float gv = 0.f;
            #pragma unroll
            for (int ni = 0; ni < 4; ++ni) {
                int col = n0 + wc * 64 + ni * 16 + l15;
                if (col == g) gv = acc[mi][ni][rr];
            }
            #pragma unroll
            for (int x = 1; x < 16; x <<= 1) gv += __shfl_xor(gv, x);
            if (l15 == 0) {
                red[lrow][wc][0] = vmax;
                red[lrow][wc][1] = se;
                red[lrow][wc][2] = gv;
            }
        }
    }
    __syncthreads();
    if (tid < 256) {
        int grow = m0 + tid;
        if (grow < MROWS) {
            float ma = red[tid][0][0], mb = red[tid][1][0];
            float M = fmaxf(ma, mb);
            float Sv = red[tid][0][1] * expf(ma - M) + red[tid][1][1] * expf(mb - M);
            float G = red[tid][0][2] + red[tid][1][2];
            size_t idx = (size_t)grow * NCH + nt;
            pmax[idx] = M; psum[idx] = Sv; pgold[idx] = G;
        }
    }
}

// ---------------- combine chunks -> logP[row] ----------------
__global__ __launch_bounds__(256) void k_lse(const float* __restrict__ pmax,
                                             const float* __restrict__ psum,
                                             const float* __restrict__ pgold,
                                             float* __restrict__ logP) {
    int item = blockIdx.x * 4 + (threadIdx.x >> 6);
    int lane = threadIdx.x & 63;
    if (item >= MROWS) return;
    float m = -1e30f, g = 0.f;
    for (int c = lane; c < NCH; c += 64) {
        size_t idx = (size_t)item * NCH + c;
        m = fmaxf(m, pmax[idx]);
        g += pgold[idx];
    }
    for (int o = 32; o; o >>= 1) m = fmaxf(m, __shfl_xor(m, o));
    float s = 0.f;
    for (int c = lane; c < NCH; c += 64) {
        size_t idx = (size_t)item * NCH + c;
        s += psum[idx] * expf(pmax[idx] - m);
    }
    for (int o = 32; o; o >>= 1) { s += __shfl_xor(s, o); g += __shfl_xor(g, o); }
    if (lane == 0) logP[item] = g - (m + logf(s));
}

__global__ __launch_bounds__(64) void k_final(const float* __restrict__ logP,
                                              float* __restrict__ out) {
    int b = threadIdx.x;
    if (b < 32) {
        float s = 0.f;
        for (int t = 0; t < TP; ++t) s += logP[t * 32 + b];
        out[b] = s;
    }
}

// ================= host =================
extern "C" void kernel_launch(void* const* d_in, const int* in_sizes, int n_in,
                              void* d_out, int out_size, void* d_ws, size_t ws_size,
                              hipStream_t stream) {
    const int*   seq_in  = (const int*)d_in[0];
    const int*   seq_tgt = (const int*)d_in[1];
    const float* src_emb = (const float*)d_in[2];
    const float* tgt_emb = (const float*)d_in[3];
    const float* eWihF = (const float*)d_in[4];
    const float* eWhhF = (const float*)d_in[5];
    const float* eBihF = (const float*)d_in[6];
    const float* eBhhF = (const float*)d_in[7];
    const float* eWihB = (const float*)d_in[8];
    const float* eWhhB = (const float*)d_in[9];
    const float* eBihB = (const float*)d_in[10];
    const float* eBhhB = (const float*)d_in[11];
    const float* dWih  = (const float*)d_in[12];
    const float* dWhh  = (const float*)d_in[13];
    const float* dBih  = (const float*)d_in[14];
    const float* dBhh  = (const float*)d_in[15];
    const float* WinH  = (const float*)d_in[16];
    const float* WinC  = (const float*)d_in[17];
    const float* Watt  = (const float*)d_in[18];
    const float* Wcomb = (const float*)d_in[19];
    const float* Wproj = (const float*)d_in[20];

    char* ws = (char*)d_ws;
    size_t off = 0;
    auto alloc = [&](size_t bytes) -> char* {
        off = (off + 255) & ~(size_t)255;
        char* p = ws + off;
        off += bytes;
        return p;
    };
    const size_t G4 = 4 * (size_t)H;
    const size_t slot = (size_t)B * H;
    // bf16 weights
    u16* wihf = (u16*)alloc(G4 * E * 2);
    u16* whhf = (u16*)alloc(G4 * H * 2);
    u16* wihb = (u16*)alloc(G4 * E * 2);
    u16* whhb = (u16*)alloc(G4 * H * 2);
    u16* dwih = (u16*)alloc(G4 * (E + H) * 2);
    u16* dwhh = (u16*)alloc(G4 * H * 2);
    u16* winh = (u16*)alloc((size_t)H * 2 * H * 2);
    u16* winc = (u16*)alloc((size_t)H * 2 * H * 2);
    u16* watt = (u16*)alloc((size_t)H * 2 * H * 2);
    u16* wcmb = (u16*)alloc((size_t)H * 3 * H * 2);
    u16* wprj = (u16*)alloc((size_t)V * H * 2);
    u16* wcmbT = (u16*)alloc((size_t)3 * H * H * 2);
    u16* wfuse = (u16*)alloc((size_t)G4 * 3 * H * 2);
    // bf16 activations
    u16* xsrc  = (u16*)alloc((size_t)S * B * E * 2);
    u16* xtgt  = (u16*)alloc((size_t)T * B * E * 2);
    u16* hsf   = (u16*)alloc((size_t)(S + 1) * slot * 2);
    u16* hsb   = (u16*)alloc((size_t)(S + 1) * slot * 2);
    u16* ench  = (u16*)alloc((size_t)B * S * 2 * H * 2);
    u16* encab = (u16*)alloc((size_t)B * S * H * 2);
    u16* hc    = (u16*)alloc((size_t)(T + 1) * B * 3072 * 2);
    u16* outsb = (u16*)alloc((size_t)(T * B) * H * 2);
    u16* lcbf  = (u16*)alloc(2 * slot * 2);
    // f32 buffers
    float* xgF  = (float*)alloc((size_t)S * B * G4 * 4);
    float* xgB  = (float*)alloc((size_t)S * B * G4 * 4);
    float* xgD  = (float*)alloc((size_t)T * B * G4 * 4);
    float* cf2  = (float*)alloc(2 * slot * 4);
    float* decc = (float*)alloc(slot * 4);
    float* pmax  = (float*)alloc((size_t)MROWS * NCH * 4);
    float* psum  = (float*)alloc((size_t)MROWS * NCH * 4);
    float* pgold = (float*)alloc((size_t)MROWS * NCH * 4);
    float* logP  = (float*)alloc((size_t)MROWS * 4);
    int* bars = (int*)alloc(3 * 2048 * 4);
    (void)ws_size; (void)in_sizes; (void)n_in; (void)out_size;

    hipMemsetAsync(hsf, 0, slot * 2, stream);
    hipMemsetAsync(hsb, 0, slot * 2, stream);
    hipMemsetAsync(hc, 0, (size_t)B * 3072 * 2, stream);   // hc[0] (ctx part = 0)
    hipMemsetAsync(bars, 0, 3 * 2048 * 4, stream);

    // merged weight conversions (11 segments, one launch)
    {
        CvtD d;
        const float* srcs[11] = {eWihF, eWhhF, eWihB, eWhhB, dWih, dWhh,
                                 WinH, WinC, Watt, Wcomb, Wproj};
        u16* dsts[11] = {wihf, whhf, wihb, whhb, dwih, dwhh,
                         winh, winc, watt, wcmb, wprj};
        size_t ns[11] = {G4 * E, G4 * H, G4 * E, G4 * H, G4 * (E + H), G4 * H,
                         (size_t)H * 2 * H, (size_t)H * 2 * H, (size_t)H * 2 * H,
                         (size_t)H * 3 * H, (size_t)V * H};
        int blk = 0;
        for (int i = 0; i < 11; ++i) {
            d.src[i] = srcs[i];
            d.dst[i] = dsts[i];
            d.n4[i] = (int)(ns[i] / 4);
            d.start[i] = blk;
            blk += (d.n4[i] + 255) / 256;
        }
        d.start[11] = blk;
        k_cvtm<<<dim3(blk), dim3(256), 0, stream>>>(d);
    }

    k_embed<<<dim3((S * B * (E / 4) + 255) / 256), dim3(256), 0, stream>>>(
        seq_in, S, S, src_emb, xsrc);
    k_embed<<<dim3((T * B * (E / 4) + 255) / 256), dim3(256), 0, stream>>>(
        seq_tgt, T, T, tgt_emb, xtgt);

    k_transp<<<dim3(3 * H / 64, H / 64), dim3(256), 0, stream>>>(wcmb, wcmbT, H, 3 * H);

    // merged prep GEMMs: xgF, xgB, xgD, wfuse in one launch (tail overlap)
    {
        T4 p;
        // seg 0: xgF = xsrc @ wihf^T
        p.A[0] = xsrc; p.astr[0] = E; p.W[0] = wihf; p.wstr[0] = E;
        p.outf[0] = xgF; p.outb[0] = nullptr; p.ostr[0] = 4096; p.kt[0] = 8; p.nx[0] = 32;
        // seg 1: xgB = xsrc @ wihb^T
        p.A[1] = xsrc; p.astr[1] = E; p.W[1] = wihb; p.wstr[1] = E;
        p.outf[1] = xgB; p.outb[1] = nullptr; p.ostr[1] = 4096; p.kt[1] = 8; p.nx[1] = 32;
        // seg 2: xgD = xtgt @ dwih^T
        p.A[2] = xtgt; p.astr[2] = E; p.W[2] = dwih; p.wstr[2] = E + H;
        p.outf[2] = xgD; p.outb[2] = nullptr; p.ostr[2] = 4096; p.kt[2] = 8; p.nx[2] = 32;
        // seg 3: wfuse = dwih_o @ wcmbT^T
        p.A[3] = dwih + E; p.astr[3] = E + H; p.W[3] = wcmbT; p.wstr[3] = H;
        p.outf[3] = nullptr; p.outb[3] = wfuse; p.ostr[3] = 3 * H; p.kt[3] = 16; p.nx[3] = 24;
        p.start[0] = 0;
        p.start[1] = 512;            // 32x16
        p.start[2] = 1024;           // 32x16
        p.start[3] = 1408;           // 32x12
        p.start[4] = 1408 + 768;     // 24x32
        k_tile4<<<dim3(p.start[4]), dim3(256), 0, stream>>>(p);
    }

    // ---------- persistent bidirectional encoder (128 blocks/dir) ----------
    k_enc<<<dim3(256), dim3(512), 0, stream>>>(xgF, xgB, whhf, whhb,
                                               eBihF, eBhhF, eBihB, eBhhB,
                                               hsf, hsb, cf2, bars);

    k_ench<<<dim3(B * S * (2 * H / 8) / 256), dim3(256), 0, stream>>>(hsf, hsb, ench);
    k_tile<<<dim3(8, 16), dim3(256), 0, stream>>>(ench, 2 * H, watt, 2 * H,
                                                  nullptr, encab, H, 32);
    {
        int n4 = (int)(2 * slot / 4);
        k_cvt<<<dim3((n4 + 255) / 256), dim3(256), 0, stream>>>(cf2, lcbf, n4);
    }

    // decoder init: dec_h0 directly into hc[0] (bf16, stride 3072); c0; xgD corr
    {
        Seg a1{hsf + (size_t)S * slot, H, winh, 2 * H, H};
        Seg a2{hsb + (size_t)S * slot, H, winh + H, 2 * H, H};
        k_mm<<<dim3(H / 16), dim3(512), 0, stream>>>(a1, a2, nullptr, hc, 3072,
                                                     2 * H / 8, 0);
        Seg c1{lcbf, H, winc, 2 * H, H};
        Seg c2{lcbf + slot, H, winc + H, 2 * H, H};
        k_mm<<<dim3(H / 16), dim3(512), 0, stream>>>(c1, c2, decc, nullptr, H,
                                                     2 * H / 8, 0);
        // xgD[0] -= hc[0] @ Wfuse_h^T   (sub-mode)
        Seg f1{hc, 3072, wfuse, 3 * H, H};
        Seg f0{nullptr, 0, nullptr, 0, 0};
        k_mm<<<dim3(G4 / 16), dim3(512), 0, stream>>>(f1, f0, xgD, nullptr, 4096,
                                                      H / 8, 1);
    }

    // ---------- persistent attention decoder ----------
    k_dec<<<dim3(256), dim3(512), 0, stream>>>(xgD, dwhh, wfuse, dBih, dBhh, decc,
                                               encab, ench, hc, bars + 4096);

    // outs = hc[1..48] @ Wcomb^T (bf16)
    k_tile<<<dim3(8, 12), dim3(256), 0, stream>>>(hc + B * 3072, 3 * H, wcmb, 3 * H,
                                                  nullptr, outsb, H, 48);

    // ---------- vocab projection + log-softmax ----------
    k_proj<<<dim3(1500), dim3(512), 0, stream>>>(outsb, wprj, seq_tgt, pmax, psum, pgold);
    k_lse<<<dim3((MROWS + 3) / 4), dim3(256), 0, stream>>>(pmax, psum, pgold, logP);
    k_final<<<dim3(1), dim3(64), 0, stream>>>(logP, (float*)d_out);
}